// Round 23
// baseline (161.060 us; speedup 1.0000x reference)
//
#include <hip/hip_runtime.h>

#define B_ 4
#define S_ 2048
#define D_ 768
#define H_ 12
#define HD_ 64
#define T_ (B_ * S_)  // 8192

typedef __bf16 bf16x8 __attribute__((ext_vector_type(8)));
typedef __bf16 bf16x4 __attribute__((ext_vector_type(4)));
typedef float  f32x4  __attribute__((ext_vector_type(4)));

__device__ __forceinline__ f32x4 mfma16(bf16x8 a, bf16x8 b, f32x4 c) {
  return __builtin_amdgcn_mfma_f32_16x16x32_bf16(a, b, c, 0, 0, 0);
}

// 2^x via v_exp_f32 (scores are pre-scaled by log2e at weight-convert time)
__device__ __forceinline__ float fexp2(float x) {
  float r;
  asm("v_exp_f32 %0, %1" : "=v"(r) : "v"(x));
  return r;
}

// async global->LDS, 16B per lane. LDS dest is wave-uniform base + lane*16.
__device__ __forceinline__ void gload16(const __bf16* g, __bf16* lds) {
  __builtin_amdgcn_global_load_lds(
      (__attribute__((address_space(1))) void*)g,
      (__attribute__((address_space(3))) void*)lds, 16, 0, 0);
}

// ---------------- fused fp32 -> bf16 convert (x + 4 weights, 1 launch) -------
__global__ void cvt_all(const float* __restrict__ x,
                        const float* __restrict__ wq,
                        const float* __restrict__ wk,
                        const float* __restrict__ wv,
                        const float* __restrict__ wo,
                        __bf16* __restrict__ out) {
  constexpr int XN4 = T_ * D_ / 4;
  constexpr int WN4 = D_ * D_ / 4;
  const int i = blockIdx.x * blockDim.x + threadIdx.x;
  if (i >= XN4 + 4 * WN4) return;
  const float* src;
  int k;
  float scale = 1.0f;
  if (i < XN4) {
    src = x;
    k = i;
  } else {
    const int j = i - XN4;
    const int wsel = j / WN4;
    k = j - wsel * WN4;
    src = (wsel == 0) ? wq : (wsel == 1) ? wk : (wsel == 2) ? wv : wo;
    if (wsel == 1) scale = 0.18033688f;  // 0.125 * log2(e)
  }
  const float4 v = reinterpret_cast<const float4*>(src)[k];
  bf16x4 o;
  o[0] = (__bf16)(v.x * scale);
  o[1] = (__bf16)(v.y * scale);
  o[2] = (__bf16)(v.z * scale);
  o[3] = (__bf16)(v.w * scale);
  reinterpret_cast<bf16x4*>(out)[i] = o;
}

// ---------------- GEMM: C[m][n] = sum_k A[m][k] * W[n][k]  (B^T layout) ------
// r23: gemm0 was FILL-PATH-BOUND (451 MB staged / 43 us = 41 GB/s/CU, at the
// demonstrated gload_lds ceiling). B (weights) doesn't need LDS: each wave's
// B-fragments are per-wave register operands -> load directly from L2
// (196 KB panel, resident) via the VECTOR path, double-buffered in registers
// with a full iteration of cover (what r18's V-direct lacked). Staged demand
// halves (A only); LDS 64->32 KB. A keeps the swizzled gload_lds + counted
// vmcnt (prologue A0,A1,Bf0; top-of-body vmcnt(12): own A landed, next A +
// next B-frags in flight). Epilogue: r22 LDS-transpose, two 8 KB passes.
template <int MODE>
__global__ __launch_bounds__(256)
__attribute__((amdgpu_waves_per_eu(2)))
void gemm_bt(const __bf16* __restrict__ A,
             const __bf16* __restrict__ W0, const __bf16* __restrict__ W1,
             const __bf16* __restrict__ W2,
             __bf16* __restrict__ Oq, __bf16* __restrict__ Ok,
             __bf16* __restrict__ Ov,
             float* __restrict__ fout, const float* __restrict__ bias) {
  constexpr int K = D_;       // 768
  constexpr int NT = K / 64;  // 12 K-tiles (even)
  __shared__ __align__(16) char smem[32768];  // loop: sA dbuf; epi: 8KB/wave
  __bf16* sA0 = reinterpret_cast<__bf16*>(smem);  // [2][128*64]

  const int tid = threadIdx.x;
  const int l = tid & 63;
  const int w = tid >> 6;

  const int flat = blockIdx.y * 64 + blockIdx.x;
  const int xcd = flat & 7;
  const int q = flat >> 3;
  const int mtile = xcd * 8 + (q & 7);
  const int pan = q >> 3;
  const int m0 = mtile * 128;

  int mat, n0;
  const __bf16* Wm;
  if (MODE == 0) {
    mat = pan / 6;
    n0 = (pan % 6) * 128;
    Wm = (mat == 0) ? W0 : (mat == 1) ? W1 : W2;
  } else {
    mat = 0;
    n0 = pan * 128;
    Wm = W0;
  }

  const int srow = l >> 3;                // 0..7
  const int scol = ((l & 7) ^ srow) * 8;  // pre-swizzled source col (A only)
  const __bf16* gA[4];
#pragma unroll
  for (int i = 0; i < 4; ++i) {
    const int c = w * 4 + i;
    gA[i] = A + (size_t)(m0 + c * 8 + srow) * K + scol;
  }

  f32x4 acc[4][4] = {};
  const int wr = w >> 1, wc = w & 1;
  const int fr = l & 15, fq = l >> 4;
  const int swz = (fr & 7) << 4;

  // per-wave B base: row n0 + wc*64 + fr, col fq*8 (B-operand layout)
  const __bf16* bp = Wm + (size_t)(n0 + wc * 64 + fr) * K + fq * 8;

  // prologue: A(0)->sA[0], A(1)->sA[1], Bf(0)->bfA
#pragma unroll
  for (int i = 0; i < 4; ++i) gload16(gA[i], &sA0[(w * 4 + i) * 512]);
#pragma unroll
  for (int i = 0; i < 4; ++i)
    gload16(gA[i] + 64, &sA0[8192 + (w * 4 + i) * 512]);
  bf16x8 bfA[4][2], bfB[4][2];
#pragma unroll
  for (int ni = 0; ni < 4; ++ni)
#pragma unroll
    for (int ks = 0; ks < 2; ++ks)
      bfA[ni][ks] = *reinterpret_cast<const bf16x8*>(
          bp + (size_t)(ni * 16) * K + ks * 32);

#define GEMM_BODY(KT, SB, BFC, BFN)                                          \
  do {                                                                       \
    if ((KT) + 1 < NT)                                                       \
      asm volatile("s_waitcnt vmcnt(12)" ::: "memory");                      \
    else                                                                     \
      asm volatile("s_waitcnt vmcnt(8)" ::: "memory");                       \
    __builtin_amdgcn_s_barrier();                                            \
    if ((KT) + 1 < NT) {                                                     \
      _Pragma("unroll") for (int ni = 0; ni < 4; ++ni)                       \
          _Pragma("unroll") for (int ks = 0; ks < 2; ++ks)                   \
              BFN[ni][ks] = *reinterpret_cast<const bf16x8*>(                \
                  bp + (size_t)(ni * 16) * K + ((KT) + 1) * 64 + ks * 32);   \
    }                                                                        \
    const char* ab = reinterpret_cast<const char*>(&sA0[(SB)*8192]);         \
    _Pragma("unroll") for (int ks = 0; ks < 2; ++ks) {                       \
      bf16x8 af[4];                                                          \
      _Pragma("unroll") for (int mi = 0; mi < 4; ++mi) af[mi] =              \
          *reinterpret_cast<const bf16x8*>(ab +                              \
                                           (wr * 64 + mi * 16 + fr) * 128 +  \
                                           ((ks * 64 + fq * 16) ^ swz));     \
      _Pragma("unroll") for (int mi = 0; mi < 4; ++mi)                       \
          _Pragma("unroll") for (int ni = 0; ni < 4; ++ni) acc[mi][ni] =     \
              mfma16(af[mi], BFC[ni][ks], acc[mi][ni]);                      \
    }                                                                        \
    __builtin_amdgcn_s_barrier();                                            \
    if ((KT) + 2 < NT) {                                                     \
      const int ko = ((KT) + 2) * 64;                                        \
      _Pragma("unroll") for (int i = 0; i < 4; ++i)                          \
          gload16(gA[i] + ko, &sA0[(SB)*8192 + (w * 4 + i) * 512]);          \
    }                                                                        \
  } while (0)

  for (int kt = 0; kt < NT; kt += 2) {
    GEMM_BODY(kt, 0, bfA, bfB);
    GEMM_BODY(kt + 1, 1, bfB, bfA);
  }
#undef GEMM_BODY

  // ---------------- epilogue ----------------
  if (MODE == 0 && mat == 2) {
    // V^T: direct vectorized store (4 consecutive s per lane -> one 8B store)
#pragma unroll
    for (int mi = 0; mi < 4; ++mi) {
      const int mbase = m0 + wr * 64 + mi * 16 + fq * 4;
      const int b = mbase >> 11, s = mbase & (S_ - 1);
#pragma unroll
      for (int ni = 0; ni < 4; ++ni) {
        const int o = n0 + wc * 64 + ni * 16 + fr;
        const int h = o >> 6, hd = o & 63;
        bf16x4 vv;
#pragma unroll
        for (int r = 0; r < 4; ++r) vv[r] = (__bf16)acc[mi][ni][r];
        *reinterpret_cast<bf16x4*>(
            &Ov[((size_t)((b * H_ + h) * HD_ + hd)) * S_ + s]) = vv;
      }
    }
  } else {
    // LDS transpose, two 8 KB passes (wave-private [32][64] f32 region)
    float* fW = reinterpret_cast<float*>(smem) + w * 2048;
#pragma unroll
    for (int half = 0; half < 2; ++half) {
#pragma unroll
      for (int mi2 = 0; mi2 < 2; ++mi2)
#pragma unroll
        for (int ni = 0; ni < 4; ++ni)
#pragma unroll
          for (int r = 0; r < 4; ++r)
            fW[(mi2 * 16 + fq * 4 + r) * 64 + ni * 16 + fr] =
                acc[half * 2 + mi2][ni][r];
      // per-wave region: lgkm ordering within the wave suffices
      if (MODE == 1) {
        const int ocol = n0 + wc * 64 + fr * 4;
        const float4 bs = *reinterpret_cast<const float4*>(&bias[ocol]);
#pragma unroll
        for (int it = 0; it < 8; ++it) {
          const int lrow = it * 4 + fq;
          f32x4 v = *reinterpret_cast<const f32x4*>(&fW[lrow * 64 + fr * 4]);
          v[0] += bs.x;
          v[1] += bs.y;
          v[2] += bs.z;
          v[3] += bs.w;
          *reinterpret_cast<f32x4*>(
              &fout[(size_t)(m0 + wr * 64 + half * 32 + lrow) * D_ + ocol]) =
              v;
        }
      } else {
        const int o = n0 + wc * 64;  // 64-aligned -> h const
        const int h = o >> 6;
        __bf16* dst = (mat == 0) ? Oq : Ok;
#pragma unroll
        for (int it = 0; it < 8; ++it) {
          const int lrow = it * 4 + fq;
          const int m = m0 + wr * 64 + half * 32 + lrow;
          const int b = m >> 11, s = m & (S_ - 1);
          const f32x4 v =
              *reinterpret_cast<const f32x4*>(&fW[lrow * 64 + fr * 4]);
          bf16x4 ov;
#pragma unroll
          for (int r = 0; r < 4; ++r) ov[r] = (__bf16)v[r];
          *reinterpret_cast<bf16x4*>(
              &dst[((size_t)((b * H_ + h) * S_ + s)) * HD_ + fr * 4]) = ov;
        }
      }
    }
  }
}

// ---------------- causal flash attention: 64-q blocks + counted-vmcnt ---------
// r22 structure + defer-max (T13): attn is now VALU-issue-bound (VALUBusy
// 45%); skipping the per-tile rescale (16 muls + 1 exp) when the running max
// doesn't grow by >8 (log2-domain; P bounded by 2^8) cuts the VALU hot path.
// (r17's null was the grid-capped regime — wrong regime for this mechanism.)
__global__ __launch_bounds__(256)
__attribute__((amdgpu_waves_per_eu(4, 4)))
void attn_kernel(const __bf16* __restrict__ Q, const __bf16* __restrict__ Kt,
                 const __bf16* __restrict__ Vt, __bf16* __restrict__ C) {
  __shared__ __align__(16) __bf16 sK[2][64 * 64];  // [kv][hd], swizzled
  __shared__ __align__(16) __bf16 sV[2][64 * 64];  // V^T [hd][kv], swizzled
  __shared__ __align__(16) __bf16 sP[4][16 * 64];  // per-warp P (2 KB)

  const int tid = threadIdx.x;
  const int l = tid & 63;
  const int w = tid >> 6;
  const int fr = l & 15, fq = l >> 4;
  const int bx = blockIdx.x;
  const int xcd = bx & 7;
  const int j = bx >> 3;             // [0, 192)
  const int bh = xcd + 8 * (j % 6);  // head in [0, 48), 6 per XCD
  const int qtile = 31 - j / 6;      // [0, 32), deep first
  const int qb = qtile * 64;
  const int qbw = qb + w * 16;  // this warp's 16 q-rows

  const __bf16* qh = Q + (size_t)bh * S_ * HD_;
  const __bf16* kh = Kt + (size_t)bh * S_ * HD_;
  const __bf16* vh = Vt + (size_t)bh * HD_ * S_;
  char* sPb = reinterpret_cast<char*>(&sP[w][0]);

  const int srow = l >> 3;                       // 0..7
  const int scol = ((l & 7) * 8) ^ (srow << 3);  // pre-swizzled source col
  const int swz = (fr & 7) << 4;                 // read-side XOR (bytes)

  bf16x8 qf[2];
#pragma unroll
  for (int ks = 0; ks < 2; ++ks)
    qf[ks] = *reinterpret_cast<const bf16x8*>(
        &qh[(size_t)(qbw + fr) * HD_ + ks * 32 + fq * 8]);

  f32x4 acc[4] = {};
  float mrow = -1e30f, lrow = 0.f;

  const int nt = qtile + 1;  // kv tiles 0 .. qb/64
  int cur = 0;
  const int q0 = 2 * w, q1 = 2 * w + 1;

  gload16(kh + (size_t)(q0 * 8 + srow) * HD_ + scol, &sK[0][q0 * 512]);
  gload16(kh + (size_t)(q1 * 8 + srow) * HD_ + scol, &sK[0][q1 * 512]);
  gload16(vh + (size_t)(q0 * 8 + srow) * S_ + scol, &sV[0][q0 * 512]);
  gload16(vh + (size_t)(q1 * 8 + srow) * S_ + scol, &sV[0][q1 * 512]);
  if (nt > 1) {
    gload16(kh + (size_t)(64 + q0 * 8 + srow) * HD_ + scol, &sK[1][q0 * 512]);
    gload16(kh + (size_t)(64 + q1 * 8 + srow) * HD_ + scol, &sK[1][q1 * 512]);
    gload16(vh + (size_t)(q0 * 8 + srow) * S_ + 64 + scol, &sV[1][q0 * 512]);
    gload16(vh + (size_t)(q1 * 8 + srow) * S_ + 64 + scol, &sV[1][q1 * 512]);
  }

  for (int t = 0; t < nt; ++t) {
    if (t + 1 < nt)
      asm volatile("s_waitcnt vmcnt(4)" ::: "memory");
    else
      asm volatile("s_waitcnt vmcnt(0)" ::: "memory");
    __builtin_amdgcn_s_barrier();  // all warps' stage(t) landed

    const int kv0 = t * 64;
    if (kv0 <= qbw + 15) {
      const char* kb = reinterpret_cast<const char*>(&sK[cur][0]);
      const char* vb = reinterpret_cast<const char*>(&sV[cur][0]);

      f32x4 s[4];
      __builtin_amdgcn_s_setprio(1);
#pragma unroll
      for (int c = 0; c < 4; ++c) {
        const int row = c * 16 + fr;
        bf16x8 kf0 = *reinterpret_cast<const bf16x8*>(
            kb + row * 128 + ((fq * 16) ^ swz));
        bf16x8 kf1 = *reinterpret_cast<const bf16x8*>(
            kb + row * 128 + ((fq * 16 + 64) ^ swz));
        f32x4 z = {};
        z = mfma16(kf0, qf[0], z);
        z = mfma16(kf1, qf[1], z);
        s[c] = z;
      }
      __builtin_amdgcn_s_setprio(0);

      if (kv0 + 63 > qbw) {
        const int qi = qbw + fr;
#pragma unroll
        for (int c = 0; c < 4; ++c)
#pragma unroll
          for (int r = 0; r < 4; ++r) {
            const int kvi = kv0 + c * 16 + fq * 4 + r;
            if (kvi > qi) s[c][r] = -1e30f;
          }
      }

      float tm = -1e30f;
#pragma unroll
      for (int c = 0; c < 4; ++c)
#pragma unroll
        for (int r = 0; r < 4; ++r) tm = fmaxf(tm, s[c][r]);
      tm = fmaxf(tm, __shfl_xor(tm, 16));
      tm = fmaxf(tm, __shfl_xor(tm, 32));
      // defer-max (T13): skip rescale while max grows <= 8 (log2-domain;
      // P bounded by 2^8, safe in f32 accum / bf16 P)
      const bool defer = __all(tm - mrow <= 8.0f);
      const float mn = defer ? mrow : fmaxf(mrow, tm);
      if (!defer) {
        const float fac = fexp2(mrow - mn);
        mrow = mn;
        lrow *= fac;
#pragma unroll
        for (int dt = 0; dt < 4; ++dt)
#pragma unroll
          for (int r = 0; r < 4; ++r) acc[dt][r] *= fac;
      }
      float sum = 0.f;
#pragma unroll
      for (int c = 0; c < 4; ++c) {
        bf16x4 pc;
#pragma unroll
        for (int r = 0; r < 4; ++r) {
          const float p = fexp2(s[c][r] - mn);
          sum += p;
          pc[r] = (__bf16)p;
        }
        const int bo = (c * 32 + fq * 8) ^ swz;
        *reinterpret_cast<bf16x4*>(sPb + fr * 128 + bo) = pc;
      }
      sum += __shfl_xor(sum, 16);
      sum += __shfl_xor(sum, 32);
      lrow += sum;

      bf16x8 pa[2];
#pragma unroll
      for (int ks = 0; ks < 2; ++ks) {
        const int bo = (ks * 64 + fq * 16) ^ swz;
        pa[ks] = *reinterpret_cast<const bf16x8*>(sPb + fr * 128 + bo);
      }

      __builtin_amdgcn_s_setprio(1);
#pragma unroll
      for (int dt = 0; dt < 4; ++dt) {
        const int row = dt * 16 + fr;
        bf16x8 vf0 = *reinterpret_cast<const bf16x8*>(
            vb + row * 128 + ((fq * 16) ^ swz));
        bf16x8 vf1 = *reinterpret_cast<const bf16x8*>(
            vb + row * 128 + ((fq * 16 + 64) ^ swz));
        acc[dt] = mfma16(vf0, pa[0], acc[dt]);
        acc[dt] = mfma16(vf1, pa[1], acc[dt]);
      }
      __builtin_amdgcn_s_setprio(0);
    }

    __builtin_amdgcn_s_barrier();  // all warps done reading buf[cur]

    if (t + 2 < nt) {
      const int kvn = (t + 2) * 64;
      gload16(kh + (size_t)(kvn + q0 * 8 + srow) * HD_ + scol,
              &sK[cur][q0 * 512]);
      gload16(kh + (size_t)(kvn + q1 * 8 + srow) * HD_ + scol,
              &sK[cur][q1 * 512]);
      gload16(vh + (size_t)(q0 * 8 + srow) * S_ + kvn + scol,
              &sV[cur][q0 * 512]);
      gload16(vh + (size_t)(q1 * 8 + srow) * S_ + kvn + scol,
              &sV[cur][q1 * 512]);
    }
    cur ^= 1;
  }

  const int b = bh / H_, h = bh % H_;
  const float inv_l = 1.0f / lrow;
  const int qrow = qbw + fr;
#pragma unroll
  for (int dt = 0; dt < 4; ++dt) {
    bf16x4 ov;
#pragma unroll
    for (int r = 0; r < 4; ++r) ov[r] = (__bf16)(acc[dt][r] * inv_l);
    *reinterpret_cast<bf16x4*>(
        &C[((size_t)(b * S_ + qrow)) * D_ + h * HD_ + dt * 16 + fq * 4]) = ov;
  }
}

// ---------------- workspace layout (bf16 elements) ---------------------------
static constexpr size_t XB_OFF = 0;
static constexpr size_t WQ_OFF = XB_OFF + (size_t)T_ * D_;
static constexpr size_t WK_OFF = WQ_OFF + (size_t)D_ * D_;
static constexpr size_t WV_OFF = WK_OFF + (size_t)D_ * D_;
static constexpr size_t WO_OFF = WV_OFF + (size_t)D_ * D_;
static constexpr size_t Q_OFF = WO_OFF + (size_t)D_ * D_;
static constexpr size_t K_OFF = Q_OFF + (size_t)T_ * D_;
static constexpr size_t V_OFF = K_OFF + (size_t)T_ * D_;
static constexpr size_t C_OFF = V_OFF + (size_t)T_ * D_;

extern "C" void kernel_launch(void* const* d_in, const int* in_sizes, int n_in,
                              void* d_out, int out_size, void* d_ws,
                              size_t ws_size, hipStream_t stream) {
  const float* x = (const float*)d_in[0];
  const float* wq = (const float*)d_in[1];
  const float* wk = (const float*)d_in[2];
  const float* wv = (const float*)d_in[3];
  const float* wo = (const float*)d_in[4];
  const float* bo = (const float*)d_in[5];
  float* out = (float*)d_out;
  __bf16* ws = (__bf16*)d_ws;

  __bf16* xb = ws + XB_OFF;
  __bf16* wqb = ws + WQ_OFF;
  __bf16* wkb = ws + WK_OFF;
  __bf16* wvb = ws + WV_OFF;
  __bf16* wob = ws + WO_OFF;
  __bf16* qbuf = ws + Q_OFF;
  __bf16* kbuf = ws + K_OFF;
  __bf16* vbuf = ws + V_OFF;
  __bf16* cbuf = ws + C_OFF;

  {
    constexpr int n4 = T_ * D_ / 4 + 4 * (D_ * D_ / 4);
    cvt_all<<<(n4 + 255) / 256, 256, 0, stream>>>(x, wq, wk, wv, wo, ws);
  }

  gemm_bt<0><<<dim3(64, 18), 256, 0, stream>>>(
      xb, wqb, wkb, wvb, qbuf, kbuf, vbuf, nullptr, nullptr);

  attn_kernel<<<dim3(1536), 256, 0, stream>>>(qbuf, kbuf, vbuf, cbuf);

  gemm_bt<1><<<dim3(64, 6), 256, 0, stream>>>(
      cbuf, wob, nullptr, nullptr, nullptr, nullptr, nullptr, out, bo);
}

// Round 24
// 116.422 us; speedup vs baseline: 1.3834x; 1.3834x over previous
//
#include <hip/hip_runtime.h>

#define B_ 4
#define S_ 2048
#define D_ 768
#define H_ 12
#define HD_ 64
#define T_ (B_ * S_)  // 8192

typedef __bf16 bf16x8 __attribute__((ext_vector_type(8)));
typedef __bf16 bf16x4 __attribute__((ext_vector_type(4)));
typedef float  f32x4  __attribute__((ext_vector_type(4)));

__device__ __forceinline__ f32x4 mfma16(bf16x8 a, bf16x8 b, f32x4 c) {
  return __builtin_amdgcn_mfma_f32_16x16x32_bf16(a, b, c, 0, 0, 0);
}

// 2^x via v_exp_f32 (scores are pre-scaled by log2e at weight-convert time)
__device__ __forceinline__ float fexp2(float x) {
  float r;
  asm("v_exp_f32 %0, %1" : "=v"(r) : "v"(x));
  return r;
}

// async global->LDS, 16B per lane. LDS dest is wave-uniform base + lane*16.
__device__ __forceinline__ void gload16(const __bf16* g, __bf16* lds) {
  __builtin_amdgcn_global_load_lds(
      (__attribute__((address_space(1))) void*)g,
      (__attribute__((address_space(3))) void*)lds, 16, 0, 0);
}

// ---------------- fused fp32 -> bf16 convert (x + 4 weights, 1 launch) -------
__global__ void cvt_all(const float* __restrict__ x,
                        const float* __restrict__ wq,
                        const float* __restrict__ wk,
                        const float* __restrict__ wv,
                        const float* __restrict__ wo,
                        __bf16* __restrict__ out) {
  constexpr int XN4 = T_ * D_ / 4;
  constexpr int WN4 = D_ * D_ / 4;
  const int i = blockIdx.x * blockDim.x + threadIdx.x;
  if (i >= XN4 + 4 * WN4) return;
  const float* src;
  int k;
  float scale = 1.0f;
  if (i < XN4) {
    src = x;
    k = i;
  } else {
    const int j = i - XN4;
    const int wsel = j / WN4;
    k = j - wsel * WN4;
    src = (wsel == 0) ? wq : (wsel == 1) ? wk : (wsel == 2) ? wv : wo;
    if (wsel == 1) scale = 0.18033688f;  // 0.125 * log2(e)
  }
  const float4 v = reinterpret_cast<const float4*>(src)[k];
  bf16x4 o;
  o[0] = (__bf16)(v.x * scale);
  o[1] = (__bf16)(v.y * scale);
  o[2] = (__bf16)(v.z * scale);
  o[3] = (__bf16)(v.w * scale);
  reinterpret_cast<bf16x4*>(out)[i] = o;
}

// ---------------- GEMM: C[m][n] = sum_k A[m][k] * W[n][k]  (B^T layout) ------
// r22-EXACT revert (r23's B-direct-from-L2 regressed 43->75 us: the B
// fragment's lane-varying row (fr) makes per-wave vector loads fully
// uncoalesced — LDS staging IS the gather->coalesce conversion; keep it).
// 128x128, BK=64, 2-deep counted-vmcnt, swizzled LDS, XCD-slab remap,
// LDS-transpose epilogue (Q/K/MODE1) + direct vectorized V^T store.
template <int MODE>
__global__ __launch_bounds__(256)
__attribute__((amdgpu_waves_per_eu(2)))
void gemm_bt(const __bf16* __restrict__ A,
             const __bf16* __restrict__ W0, const __bf16* __restrict__ W1,
             const __bf16* __restrict__ W2,
             __bf16* __restrict__ Oq, __bf16* __restrict__ Ok,
             __bf16* __restrict__ Ov,
             float* __restrict__ fout, const float* __restrict__ bias) {
  constexpr int K = D_;       // 768
  constexpr int NT = K / 64;  // 12 K-tiles
  __shared__ __align__(16) char smem[65536];  // loop: sA|sB; epilogue: f32 x4
  __bf16* sA0 = reinterpret_cast<__bf16*>(smem);          // [2][128*64]
  __bf16* sB0 = reinterpret_cast<__bf16*>(smem + 32768);  // [2][128*64]

  const int tid = threadIdx.x;
  const int l = tid & 63;
  const int w = tid >> 6;

  const int flat = blockIdx.y * 64 + blockIdx.x;
  const int xcd = flat & 7;
  const int q = flat >> 3;
  const int mtile = xcd * 8 + (q & 7);
  const int pan = q >> 3;
  const int m0 = mtile * 128;

  int mat, n0;
  const __bf16* Wm;
  if (MODE == 0) {
    mat = pan / 6;
    n0 = (pan % 6) * 128;
    Wm = (mat == 0) ? W0 : (mat == 1) ? W1 : W2;
  } else {
    mat = 0;
    n0 = pan * 128;
    Wm = W0;
  }

  const int srow = l >> 3;                // 0..7
  const int scol = ((l & 7) ^ srow) * 8;  // source col (elements)
  const __bf16* gA[4];
  const __bf16* gB[4];
#pragma unroll
  for (int i = 0; i < 4; ++i) {
    const int c = w * 4 + i;
    gA[i] = A + (size_t)(m0 + c * 8 + srow) * K + scol;
    gB[i] = Wm + (size_t)(n0 + c * 8 + srow) * K + scol;
  }

  f32x4 acc[4][4] = {};
  const int wr = w >> 1, wc = w & 1;
  const int fr = l & 15, fq = l >> 4;
  const int swz = (fr & 7) << 4;

#pragma unroll
  for (int i = 0; i < 4; ++i) {
    const int c = w * 4 + i;
    gload16(gA[i], &sA0[c * 512]);
    gload16(gB[i], &sB0[c * 512]);
  }
#pragma unroll
  for (int i = 0; i < 4; ++i) {
    const int c = w * 4 + i;
    gload16(gA[i] + 64, &sA0[8192 + c * 512]);
    gload16(gB[i] + 64, &sB0[8192 + c * 512]);
  }

  int cur = 0;
  for (int kt = 0; kt < NT; ++kt) {
    if (kt + 1 < NT)
      asm volatile("s_waitcnt vmcnt(8)" ::: "memory");
    else
      asm volatile("s_waitcnt vmcnt(0)" ::: "memory");
    __builtin_amdgcn_s_barrier();

    const char* ab = reinterpret_cast<const char*>(&sA0[cur * 8192]);
    const char* bb = reinterpret_cast<const char*>(&sB0[cur * 8192]);
#pragma unroll
    for (int ks = 0; ks < 2; ++ks) {
      bf16x8 af[4], bfr[4];
#pragma unroll
      for (int mi = 0; mi < 4; ++mi)
        af[mi] = *reinterpret_cast<const bf16x8*>(
            ab + (wr * 64 + mi * 16 + fr) * 128 +
            ((ks * 64 + fq * 16) ^ swz));
#pragma unroll
      for (int ni = 0; ni < 4; ++ni)
        bfr[ni] = *reinterpret_cast<const bf16x8*>(
            bb + (wc * 64 + ni * 16 + fr) * 128 +
            ((ks * 64 + fq * 16) ^ swz));
#pragma unroll
      for (int mi = 0; mi < 4; ++mi)
#pragma unroll
        for (int ni = 0; ni < 4; ++ni)
          acc[mi][ni] = mfma16(af[mi], bfr[ni], acc[mi][ni]);
    }
    __builtin_amdgcn_s_barrier();

    if (kt + 2 < NT) {
      const int ko = (kt + 2) * 64;
#pragma unroll
      for (int i = 0; i < 4; ++i) {
        const int c = w * 4 + i;
        gload16(gA[i] + ko, &sA0[cur * 8192 + c * 512]);
        gload16(gB[i] + ko, &sB0[cur * 8192 + c * 512]);
      }
    }
    cur ^= 1;
  }

  // ---------------- epilogue ----------------
  if (MODE == 0 && mat == 2) {
    // V^T: direct vectorized store (4 consecutive s per lane -> one 8B store)
#pragma unroll
    for (int mi = 0; mi < 4; ++mi) {
      const int mbase = m0 + wr * 64 + mi * 16 + fq * 4;
      const int b = mbase >> 11, s = mbase & (S_ - 1);
#pragma unroll
      for (int ni = 0; ni < 4; ++ni) {
        const int o = n0 + wc * 64 + ni * 16 + fr;
        const int h = o >> 6, hd = o & 63;
        bf16x4 vv;
#pragma unroll
        for (int r = 0; r < 4; ++r) vv[r] = (__bf16)acc[mi][ni][r];
        *reinterpret_cast<bf16x4*>(
            &Ov[((size_t)((b * H_ + h) * HD_ + hd)) * S_ + s]) = vv;
      }
    }
  } else {
    // LDS transpose: wave-private [64][64] f32 region (16 KB each)
    float* fW = reinterpret_cast<float*>(smem) + w * 4096;
#pragma unroll
    for (int mi = 0; mi < 4; ++mi)
#pragma unroll
      for (int ni = 0; ni < 4; ++ni)
#pragma unroll
        for (int r = 0; r < 4; ++r)
          fW[(mi * 16 + fq * 4 + r) * 64 + ni * 16 + fr] = acc[mi][ni][r];
    // per-wave region: no barrier needed (lgkmcnt ordering is per-wave)
    if (MODE == 1) {
      const int ocol = n0 + wc * 64 + fr * 4;
      const float4 bs = *reinterpret_cast<const float4*>(&bias[ocol]);
#pragma unroll
      for (int it = 0; it < 16; ++it) {
        const int lrow = it * 4 + fq;
        f32x4 v = *reinterpret_cast<const f32x4*>(&fW[lrow * 64 + fr * 4]);
        v[0] += bs.x;
        v[1] += bs.y;
        v[2] += bs.z;
        v[3] += bs.w;
        *reinterpret_cast<f32x4*>(
            &fout[(size_t)(m0 + wr * 64 + lrow) * D_ + ocol]) = v;
      }
    } else {
      const int o = n0 + wc * 64;  // 64-aligned -> h const, hd = lcol
      const int h = o >> 6;
      __bf16* dst = (mat == 0) ? Oq : Ok;
#pragma unroll
      for (int it = 0; it < 16; ++it) {
        const int lrow = it * 4 + fq;
        const int m = m0 + wr * 64 + lrow;
        const int b = m >> 11, s = m & (S_ - 1);
        const f32x4 v =
            *reinterpret_cast<const f32x4*>(&fW[lrow * 64 + fr * 4]);
        bf16x4 ov;
#pragma unroll
        for (int r = 0; r < 4; ++r) ov[r] = (__bf16)v[r];
        *reinterpret_cast<bf16x4*>(
            &dst[((size_t)((b * H_ + h) * S_ + s)) * HD_ + fr * 4]) = ov;
      }
    }
  }
}

// ---------------- causal flash attention: 64-q blocks + counted-vmcnt ---------
// r22 structure + defer-max (T13) kept from r23 (unattributed there — the
// gemm regression masked it; this round's dispatch table isolates it).
__global__ __launch_bounds__(256)
__attribute__((amdgpu_waves_per_eu(4, 4)))
void attn_kernel(const __bf16* __restrict__ Q, const __bf16* __restrict__ Kt,
                 const __bf16* __restrict__ Vt, __bf16* __restrict__ C) {
  __shared__ __align__(16) __bf16 sK[2][64 * 64];  // [kv][hd], swizzled
  __shared__ __align__(16) __bf16 sV[2][64 * 64];  // V^T [hd][kv], swizzled
  __shared__ __align__(16) __bf16 sP[4][16 * 64];  // per-warp P (2 KB)

  const int tid = threadIdx.x;
  const int l = tid & 63;
  const int w = tid >> 6;
  const int fr = l & 15, fq = l >> 4;
  const int bx = blockIdx.x;
  const int xcd = bx & 7;
  const int j = bx >> 3;             // [0, 192)
  const int bh = xcd + 8 * (j % 6);  // head in [0, 48), 6 per XCD
  const int qtile = 31 - j / 6;      // [0, 32), deep first
  const int qb = qtile * 64;
  const int qbw = qb + w * 16;  // this warp's 16 q-rows

  const __bf16* qh = Q + (size_t)bh * S_ * HD_;
  const __bf16* kh = Kt + (size_t)bh * S_ * HD_;
  const __bf16* vh = Vt + (size_t)bh * HD_ * S_;
  char* sPb = reinterpret_cast<char*>(&sP[w][0]);

  const int srow = l >> 3;                       // 0..7
  const int scol = ((l & 7) * 8) ^ (srow << 3);  // pre-swizzled source col
  const int swz = (fr & 7) << 4;                 // read-side XOR (bytes)

  bf16x8 qf[2];
#pragma unroll
  for (int ks = 0; ks < 2; ++ks)
    qf[ks] = *reinterpret_cast<const bf16x8*>(
        &qh[(size_t)(qbw + fr) * HD_ + ks * 32 + fq * 8]);

  f32x4 acc[4] = {};
  float mrow = -1e30f, lrow = 0.f;

  const int nt = qtile + 1;  // kv tiles 0 .. qb/64
  int cur = 0;
  const int q0 = 2 * w, q1 = 2 * w + 1;

  gload16(kh + (size_t)(q0 * 8 + srow) * HD_ + scol, &sK[0][q0 * 512]);
  gload16(kh + (size_t)(q1 * 8 + srow) * HD_ + scol, &sK[0][q1 * 512]);
  gload16(vh + (size_t)(q0 * 8 + srow) * S_ + scol, &sV[0][q0 * 512]);
  gload16(vh + (size_t)(q1 * 8 + srow) * S_ + scol, &sV[0][q1 * 512]);
  if (nt > 1) {
    gload16(kh + (size_t)(64 + q0 * 8 + srow) * HD_ + scol, &sK[1][q0 * 512]);
    gload16(kh + (size_t)(64 + q1 * 8 + srow) * HD_ + scol, &sK[1][q1 * 512]);
    gload16(vh + (size_t)(q0 * 8 + srow) * S_ + 64 + scol, &sV[1][q0 * 512]);
    gload16(vh + (size_t)(q1 * 8 + srow) * S_ + 64 + scol, &sV[1][q1 * 512]);
  }

  for (int t = 0; t < nt; ++t) {
    if (t + 1 < nt)
      asm volatile("s_waitcnt vmcnt(4)" ::: "memory");
    else
      asm volatile("s_waitcnt vmcnt(0)" ::: "memory");
    __builtin_amdgcn_s_barrier();  // all warps' stage(t) landed

    const int kv0 = t * 64;
    if (kv0 <= qbw + 15) {
      const char* kb = reinterpret_cast<const char*>(&sK[cur][0]);
      const char* vb = reinterpret_cast<const char*>(&sV[cur][0]);

      f32x4 s[4];
      __builtin_amdgcn_s_setprio(1);
#pragma unroll
      for (int c = 0; c < 4; ++c) {
        const int row = c * 16 + fr;
        bf16x8 kf0 = *reinterpret_cast<const bf16x8*>(
            kb + row * 128 + ((fq * 16) ^ swz));
        bf16x8 kf1 = *reinterpret_cast<const bf16x8*>(
            kb + row * 128 + ((fq * 16 + 64) ^ swz));
        f32x4 z = {};
        z = mfma16(kf0, qf[0], z);
        z = mfma16(kf1, qf[1], z);
        s[c] = z;
      }
      __builtin_amdgcn_s_setprio(0);

      if (kv0 + 63 > qbw) {
        const int qi = qbw + fr;
#pragma unroll
        for (int c = 0; c < 4; ++c)
#pragma unroll
          for (int r = 0; r < 4; ++r) {
            const int kvi = kv0 + c * 16 + fq * 4 + r;
            if (kvi > qi) s[c][r] = -1e30f;
          }
      }

      float tm = -1e30f;
#pragma unroll
      for (int c = 0; c < 4; ++c)
#pragma unroll
        for (int r = 0; r < 4; ++r) tm = fmaxf(tm, s[c][r]);
      tm = fmaxf(tm, __shfl_xor(tm, 16));
      tm = fmaxf(tm, __shfl_xor(tm, 32));
      // defer-max (T13): skip rescale while max grows <= 8 (log2-domain;
      // P bounded by 2^8, safe in f32 accum / bf16 P)
      const bool defer = __all(tm - mrow <= 8.0f);
      const float mn = defer ? mrow : fmaxf(mrow, tm);
      if (!defer) {
        const float fac = fexp2(mrow - mn);
        mrow = mn;
        lrow *= fac;
#pragma unroll
        for (int dt = 0; dt < 4; ++dt)
#pragma unroll
          for (int r = 0; r < 4; ++r) acc[dt][r] *= fac;
      }
      float sum = 0.f;
#pragma unroll
      for (int c = 0; c < 4; ++c) {
        bf16x4 pc;
#pragma unroll
        for (int r = 0; r < 4; ++r) {
          const float p = fexp2(s[c][r] - mn);
          sum += p;
          pc[r] = (__bf16)p;
        }
        const int bo = (c * 32 + fq * 8) ^ swz;
        *reinterpret_cast<bf16x4*>(sPb + fr * 128 + bo) = pc;
      }
      sum += __shfl_xor(sum, 16);
      sum += __shfl_xor(sum, 32);
      lrow += sum;

      bf16x8 pa[2];
#pragma unroll
      for (int ks = 0; ks < 2; ++ks) {
        const int bo = (ks * 64 + fq * 16) ^ swz;
        pa[ks] = *reinterpret_cast<const bf16x8*>(sPb + fr * 128 + bo);
      }

      __builtin_amdgcn_s_setprio(1);
#pragma unroll
      for (int dt = 0; dt < 4; ++dt) {
        const int row = dt * 16 + fr;
        bf16x8 vf0 = *reinterpret_cast<const bf16x8*>(
            vb + row * 128 + ((fq * 16) ^ swz));
        bf16x8 vf1 = *reinterpret_cast<const bf16x8*>(
            vb + row * 128 + ((fq * 16 + 64) ^ swz));
        acc[dt] = mfma16(vf0, pa[0], acc[dt]);
        acc[dt] = mfma16(vf1, pa[1], acc[dt]);
      }
      __builtin_amdgcn_s_setprio(0);
    }

    __builtin_amdgcn_s_barrier();  // all warps done reading buf[cur]

    if (t + 2 < nt) {
      const int kvn = (t + 2) * 64;
      gload16(kh + (size_t)(kvn + q0 * 8 + srow) * HD_ + scol,
              &sK[cur][q0 * 512]);
      gload16(kh + (size_t)(kvn + q1 * 8 + srow) * HD_ + scol,
              &sK[cur][q1 * 512]);
      gload16(vh + (size_t)(q0 * 8 + srow) * S_ + kvn + scol,
              &sV[cur][q0 * 512]);
      gload16(vh + (size_t)(q1 * 8 + srow) * S_ + kvn + scol,
              &sV[cur][q1 * 512]);
    }
    cur ^= 1;
  }

  const int b = bh / H_, h = bh % H_;
  const float inv_l = 1.0f / lrow;
  const int qrow = qbw + fr;
#pragma unroll
  for (int dt = 0; dt < 4; ++dt) {
    bf16x4 ov;
#pragma unroll
    for (int r = 0; r < 4; ++r) ov[r] = (__bf16)(acc[dt][r] * inv_l);
    *reinterpret_cast<bf16x4*>(
        &C[((size_t)(b * S_ + qrow)) * D_ + h * HD_ + dt * 16 + fq * 4]) = ov;
  }
}

// ---------------- workspace layout (bf16 elements) ---------------------------
static constexpr size_t XB_OFF = 0;
static constexpr size_t WQ_OFF = XB_OFF + (size_t)T_ * D_;
static constexpr size_t WK_OFF = WQ_OFF + (size_t)D_ * D_;
static constexpr size_t WV_OFF = WK_OFF + (size_t)D_ * D_;
static constexpr size_t WO_OFF = WV_OFF + (size_t)D_ * D_;
static constexpr size_t Q_OFF = WO_OFF + (size_t)D_ * D_;
static constexpr size_t K_OFF = Q_OFF + (size_t)T_ * D_;
static constexpr size_t V_OFF = K_OFF + (size_t)T_ * D_;
static constexpr size_t C_OFF = V_OFF + (size_t)T_ * D_;

extern "C" void kernel_launch(void* const* d_in, const int* in_sizes, int n_in,
                              void* d_out, int out_size, void* d_ws,
                              size_t ws_size, hipStream_t stream) {
  const float* x = (const float*)d_in[0];
  const float* wq = (const float*)d_in[1];
  const float* wk = (const float*)d_in[2];
  const float* wv = (const float*)d_in[3];
  const float* wo = (const float*)d_in[4];
  const float* bo = (const float*)d_in[5];
  float* out = (float*)d_out;
  __bf16* ws = (__bf16*)d_ws;

  __bf16* xb = ws + XB_OFF;
  __bf16* wqb = ws + WQ_OFF;
  __bf16* wkb = ws + WK_OFF;
  __bf16* wvb = ws + WV_OFF;
  __bf16* wob = ws + WO_OFF;
  __bf16* qbuf = ws + Q_OFF;
  __bf16* kbuf = ws + K_OFF;
  __bf16* vbuf = ws + V_OFF;
  __bf16* cbuf = ws + C_OFF;

  {
    constexpr int n4 = T_ * D_ / 4 + 4 * (D_ * D_ / 4);
    cvt_all<<<(n4 + 255) / 256, 256, 0, stream>>>(x, wq, wk, wv, wo, ws);
  }

  gemm_bt<0><<<dim3(64, 18), 256, 0, stream>>>(
      xb, wqb, wkb, wvb, qbuf, kbuf, vbuf, nullptr, nullptr);

  attn_kernel<<<dim3(1536), 256, 0, stream>>>(qbuf, kbuf, vbuf, cbuf);

  gemm_bt<1><<<dim3(64, 6), 256, 0, stream>>>(
      cbuf, wob, nullptr, nullptr, nullptr, nullptr, nullptr, out, bo);
}

// Round 25
// 115.276 us; speedup vs baseline: 1.3972x; 1.0099x over previous
//
#include <hip/hip_runtime.h>

#define B_ 4
#define S_ 2048
#define D_ 768
#define H_ 12
#define HD_ 64
#define T_ (B_ * S_)  // 8192

typedef __bf16 bf16x8 __attribute__((ext_vector_type(8)));
typedef __bf16 bf16x4 __attribute__((ext_vector_type(4)));
typedef float  f32x4  __attribute__((ext_vector_type(4)));

__device__ __forceinline__ f32x4 mfma16(bf16x8 a, bf16x8 b, f32x4 c) {
  return __builtin_amdgcn_mfma_f32_16x16x32_bf16(a, b, c, 0, 0, 0);
}

// 2^x via v_exp_f32 (scores are pre-scaled by log2e at weight-convert time)
__device__ __forceinline__ float fexp2(float x) {
  float r;
  asm("v_exp_f32 %0, %1" : "=v"(r) : "v"(x));
  return r;
}

// async global->LDS, 16B per lane. LDS dest is wave-uniform base + lane*16.
__device__ __forceinline__ void gload16(const __bf16* g, __bf16* lds) {
  __builtin_amdgcn_global_load_lds(
      (__attribute__((address_space(1))) void*)g,
      (__attribute__((address_space(3))) void*)lds, 16, 0, 0);
}

// ---------------- fused fp32 -> bf16 convert (x + 4 weights, 1 launch) -------
__global__ void cvt_all(const float* __restrict__ x,
                        const float* __restrict__ wq,
                        const float* __restrict__ wk,
                        const float* __restrict__ wv,
                        const float* __restrict__ wo,
                        __bf16* __restrict__ out) {
  constexpr int XN4 = T_ * D_ / 4;
  constexpr int WN4 = D_ * D_ / 4;
  const int i = blockIdx.x * blockDim.x + threadIdx.x;
  if (i >= XN4 + 4 * WN4) return;
  const float* src;
  int k;
  float scale = 1.0f;
  if (i < XN4) {
    src = x;
    k = i;
  } else {
    const int j = i - XN4;
    const int wsel = j / WN4;
    k = j - wsel * WN4;
    src = (wsel == 0) ? wq : (wsel == 1) ? wk : (wsel == 2) ? wv : wo;
    if (wsel == 1) scale = 0.18033688f;  // 0.125 * log2(e)
  }
  const float4 v = reinterpret_cast<const float4*>(src)[k];
  bf16x4 o;
  o[0] = (__bf16)(v.x * scale);
  o[1] = (__bf16)(v.y * scale);
  o[2] = (__bf16)(v.z * scale);
  o[3] = (__bf16)(v.w * scale);
  reinterpret_cast<bf16x4*>(out)[i] = o;
}

// ---------------- GEMM: C[m][n] = sum_k A[m][k] * W[n][k]  (B^T layout) ------
// r22/r24-exact: 128x128, BK=64, 2-deep counted-vmcnt, swizzled LDS,
// XCD-slab remap, LDS-transpose epilogue + direct vectorized V^T store.
template <int MODE>
__global__ __launch_bounds__(256)
__attribute__((amdgpu_waves_per_eu(2)))
void gemm_bt(const __bf16* __restrict__ A,
             const __bf16* __restrict__ W0, const __bf16* __restrict__ W1,
             const __bf16* __restrict__ W2,
             __bf16* __restrict__ Oq, __bf16* __restrict__ Ok,
             __bf16* __restrict__ Ov,
             float* __restrict__ fout, const float* __restrict__ bias) {
  constexpr int K = D_;       // 768
  constexpr int NT = K / 64;  // 12 K-tiles
  __shared__ __align__(16) char smem[65536];  // loop: sA|sB; epilogue: f32 x4
  __bf16* sA0 = reinterpret_cast<__bf16*>(smem);          // [2][128*64]
  __bf16* sB0 = reinterpret_cast<__bf16*>(smem + 32768);  // [2][128*64]

  const int tid = threadIdx.x;
  const int l = tid & 63;
  const int w = tid >> 6;

  const int flat = blockIdx.y * 64 + blockIdx.x;
  const int xcd = flat & 7;
  const int q = flat >> 3;
  const int mtile = xcd * 8 + (q & 7);
  const int pan = q >> 3;
  const int m0 = mtile * 128;

  int mat, n0;
  const __bf16* Wm;
  if (MODE == 0) {
    mat = pan / 6;
    n0 = (pan % 6) * 128;
    Wm = (mat == 0) ? W0 : (mat == 1) ? W1 : W2;
  } else {
    mat = 0;
    n0 = pan * 128;
    Wm = W0;
  }

  const int srow = l >> 3;                // 0..7
  const int scol = ((l & 7) ^ srow) * 8;  // source col (elements)
  const __bf16* gA[4];
  const __bf16* gB[4];
#pragma unroll
  for (int i = 0; i < 4; ++i) {
    const int c = w * 4 + i;
    gA[i] = A + (size_t)(m0 + c * 8 + srow) * K + scol;
    gB[i] = Wm + (size_t)(n0 + c * 8 + srow) * K + scol;
  }

  f32x4 acc[4][4] = {};
  const int wr = w >> 1, wc = w & 1;
  const int fr = l & 15, fq = l >> 4;
  const int swz = (fr & 7) << 4;

#pragma unroll
  for (int i = 0; i < 4; ++i) {
    const int c = w * 4 + i;
    gload16(gA[i], &sA0[c * 512]);
    gload16(gB[i], &sB0[c * 512]);
  }
#pragma unroll
  for (int i = 0; i < 4; ++i) {
    const int c = w * 4 + i;
    gload16(gA[i] + 64, &sA0[8192 + c * 512]);
    gload16(gB[i] + 64, &sB0[8192 + c * 512]);
  }

  int cur = 0;
  for (int kt = 0; kt < NT; ++kt) {
    if (kt + 1 < NT)
      asm volatile("s_waitcnt vmcnt(8)" ::: "memory");
    else
      asm volatile("s_waitcnt vmcnt(0)" ::: "memory");
    __builtin_amdgcn_s_barrier();

    const char* ab = reinterpret_cast<const char*>(&sA0[cur * 8192]);
    const char* bb = reinterpret_cast<const char*>(&sB0[cur * 8192]);
#pragma unroll
    for (int ks = 0; ks < 2; ++ks) {
      bf16x8 af[4], bfr[4];
#pragma unroll
      for (int mi = 0; mi < 4; ++mi)
        af[mi] = *reinterpret_cast<const bf16x8*>(
            ab + (wr * 64 + mi * 16 + fr) * 128 +
            ((ks * 64 + fq * 16) ^ swz));
#pragma unroll
      for (int ni = 0; ni < 4; ++ni)
        bfr[ni] = *reinterpret_cast<const bf16x8*>(
            bb + (wc * 64 + ni * 16 + fr) * 128 +
            ((ks * 64 + fq * 16) ^ swz));
#pragma unroll
      for (int mi = 0; mi < 4; ++mi)
#pragma unroll
        for (int ni = 0; ni < 4; ++ni)
          acc[mi][ni] = mfma16(af[mi], bfr[ni], acc[mi][ni]);
    }
    __builtin_amdgcn_s_barrier();

    if (kt + 2 < NT) {
      const int ko = (kt + 2) * 64;
#pragma unroll
      for (int i = 0; i < 4; ++i) {
        const int c = w * 4 + i;
        gload16(gA[i] + ko, &sA0[cur * 8192 + c * 512]);
        gload16(gB[i] + ko, &sB0[cur * 8192 + c * 512]);
      }
    }
    cur ^= 1;
  }

  // ---------------- epilogue ----------------
  if (MODE == 0 && mat == 2) {
#pragma unroll
    for (int mi = 0; mi < 4; ++mi) {
      const int mbase = m0 + wr * 64 + mi * 16 + fq * 4;
      const int b = mbase >> 11, s = mbase & (S_ - 1);
#pragma unroll
      for (int ni = 0; ni < 4; ++ni) {
        const int o = n0 + wc * 64 + ni * 16 + fr;
        const int h = o >> 6, hd = o & 63;
        bf16x4 vv;
#pragma unroll
        for (int r = 0; r < 4; ++r) vv[r] = (__bf16)acc[mi][ni][r];
        *reinterpret_cast<bf16x4*>(
            &Ov[((size_t)((b * H_ + h) * HD_ + hd)) * S_ + s]) = vv;
      }
    }
  } else {
    float* fW = reinterpret_cast<float*>(smem) + w * 4096;
#pragma unroll
    for (int mi = 0; mi < 4; ++mi)
#pragma unroll
      for (int ni = 0; ni < 4; ++ni)
#pragma unroll
        for (int r = 0; r < 4; ++r)
          fW[(mi * 16 + fq * 4 + r) * 64 + ni * 16 + fr] = acc[mi][ni][r];
    if (MODE == 1) {
      const int ocol = n0 + wc * 64 + fr * 4;
      const float4 bs = *reinterpret_cast<const float4*>(&bias[ocol]);
#pragma unroll
      for (int it = 0; it < 16; ++it) {
        const int lrow = it * 4 + fq;
        f32x4 v = *reinterpret_cast<const f32x4*>(&fW[lrow * 64 + fr * 4]);
        v[0] += bs.x;
        v[1] += bs.y;
        v[2] += bs.z;
        v[3] += bs.w;
        *reinterpret_cast<f32x4*>(
            &fout[(size_t)(m0 + wr * 64 + lrow) * D_ + ocol]) = v;
      }
    } else {
      const int o = n0 + wc * 64;
      const int h = o >> 6;
      __bf16* dst = (mat == 0) ? Oq : Ok;
#pragma unroll
      for (int it = 0; it < 16; ++it) {
        const int lrow = it * 4 + fq;
        const int m = m0 + wr * 64 + lrow;
        const int b = m >> 11, s = m & (S_ - 1);
        const f32x4 v =
            *reinterpret_cast<const f32x4*>(&fW[lrow * 64 + fr * 4]);
        bf16x4 ov;
#pragma unroll
        for (int r = 0; r < 4; ++r) ov[r] = (__bf16)v[r];
        *reinterpret_cast<bf16x4*>(
            &dst[((size_t)((b * H_ + h) * S_ + s)) * HD_ + fr * 4]) = ov;
      }
    }
  }
}

// ---------------- causal flash attention: 64-q blocks, single-buffer V -------
// r25: LDS 40->32 KB by SINGLE-BUFFERING V (V(t) is consumed only in PV(t);
// the post-compute barrier separates PV(t) reads from the V(t+1) write) ->
// 5 blocks/CU resident (was 4), grid 6/CU. FIFO vmcnt: issue order per iter
// is V(t+1) then K(t+2); top-of-loop vmcnt(2) leaves only K(t+2) in flight,
// forcing K(t+1)+V(t+1) landed. Also: per-tile l-sum cross-lane shfl pair
// DEFERRED to epilogue (fac is uniform across the 4 lanes per q-row, so
// rescaling per-lane partial sums is exact). r15 lesson honored: VGPR ~52,
// no spill -> hand-counted vmcnt stays valid.
__global__ __launch_bounds__(256)
__attribute__((amdgpu_waves_per_eu(5)))
void attn_kernel(const __bf16* __restrict__ Q, const __bf16* __restrict__ Kt,
                 const __bf16* __restrict__ Vt, __bf16* __restrict__ C) {
  __shared__ __align__(16) __bf16 sK[2][64 * 64];  // [kv][hd], swizzled, dbuf
  __shared__ __align__(16) __bf16 sV[64 * 64];     // V^T [hd][kv], single buf
  __shared__ __align__(16) __bf16 sP[4][16 * 64];  // per-warp P (2 KB)

  const int tid = threadIdx.x;
  const int l = tid & 63;
  const int w = tid >> 6;
  const int fr = l & 15, fq = l >> 4;
  const int bx = blockIdx.x;
  const int xcd = bx & 7;
  const int j = bx >> 3;             // [0, 192)
  const int bh = xcd + 8 * (j % 6);  // head in [0, 48), 6 per XCD
  const int qtile = 31 - j / 6;      // [0, 32), deep first
  const int qb = qtile * 64;
  const int qbw = qb + w * 16;  // this warp's 16 q-rows

  const __bf16* qh = Q + (size_t)bh * S_ * HD_;
  const __bf16* kh = Kt + (size_t)bh * S_ * HD_;
  const __bf16* vh = Vt + (size_t)bh * HD_ * S_;
  char* sPb = reinterpret_cast<char*>(&sP[w][0]);

  const int srow = l >> 3;                       // 0..7
  const int scol = ((l & 7) * 8) ^ (srow << 3);  // pre-swizzled source col
  const int swz = (fr & 7) << 4;                 // read-side XOR (bytes)

  bf16x8 qf[2];
#pragma unroll
  for (int ks = 0; ks < 2; ++ks)
    qf[ks] = *reinterpret_cast<const bf16x8*>(
        &qh[(size_t)(qbw + fr) * HD_ + ks * 32 + fq * 8]);

  f32x4 acc[4] = {};
  float mrow = -1e30f, lrow = 0.f;  // lrow: per-lane PARTIAL sum (deferred)

  const int nt = qtile + 1;  // kv tiles 0 .. qb/64
  int cur = 0;
  const int q0 = 2 * w, q1 = 2 * w + 1;

  // prologue order (FIFO): K0, V0, [K1]  -> top-of-iter0 vmcnt(2) completes
  // K0+V0 with K1 in flight.
  gload16(kh + (size_t)(q0 * 8 + srow) * HD_ + scol, &sK[0][q0 * 512]);
  gload16(kh + (size_t)(q1 * 8 + srow) * HD_ + scol, &sK[0][q1 * 512]);
  gload16(vh + (size_t)(q0 * 8 + srow) * S_ + scol, &sV[q0 * 512]);
  gload16(vh + (size_t)(q1 * 8 + srow) * S_ + scol, &sV[q1 * 512]);
  if (nt > 1) {
    gload16(kh + (size_t)(64 + q0 * 8 + srow) * HD_ + scol, &sK[1][q0 * 512]);
    gload16(kh + (size_t)(64 + q1 * 8 + srow) * HD_ + scol, &sK[1][q1 * 512]);
  }

  for (int t = 0; t < nt; ++t) {
    // complete all but the newest 2 loads (= K(t+1)); K(t)+V(t) landed
    if (t + 1 < nt)
      asm volatile("s_waitcnt vmcnt(2)" ::: "memory");
    else
      asm volatile("s_waitcnt vmcnt(0)" ::: "memory");
    __builtin_amdgcn_s_barrier();  // all warps' stage(t) landed

    const int kv0 = t * 64;
    if (kv0 <= qbw + 15) {
      const char* kb = reinterpret_cast<const char*>(&sK[cur][0]);
      const char* vb = reinterpret_cast<const char*>(&sV[0]);

      f32x4 s[4];
      __builtin_amdgcn_s_setprio(1);
#pragma unroll
      for (int c = 0; c < 4; ++c) {
        const int row = c * 16 + fr;
        bf16x8 kf0 = *reinterpret_cast<const bf16x8*>(
            kb + row * 128 + ((fq * 16) ^ swz));
        bf16x8 kf1 = *reinterpret_cast<const bf16x8*>(
            kb + row * 128 + ((fq * 16 + 64) ^ swz));
        f32x4 z = {};
        z = mfma16(kf0, qf[0], z);
        z = mfma16(kf1, qf[1], z);
        s[c] = z;
      }
      __builtin_amdgcn_s_setprio(0);

      if (kv0 + 63 > qbw) {
        const int qi = qbw + fr;
#pragma unroll
        for (int c = 0; c < 4; ++c)
#pragma unroll
          for (int r = 0; r < 4; ++r) {
            const int kvi = kv0 + c * 16 + fq * 4 + r;
            if (kvi > qi) s[c][r] = -1e30f;
          }
      }

      float tm = -1e30f;
#pragma unroll
      for (int c = 0; c < 4; ++c)
#pragma unroll
        for (int r = 0; r < 4; ++r) tm = fmaxf(tm, s[c][r]);
      tm = fmaxf(tm, __shfl_xor(tm, 16));
      tm = fmaxf(tm, __shfl_xor(tm, 32));
      // defer-max (T13): skip rescale while max grows <= 8 (log2-domain)
      const bool defer = __all(tm - mrow <= 8.0f);
      const float mn = defer ? mrow : fmaxf(mrow, tm);
      if (!defer) {
        const float fac = fexp2(mrow - mn);  // uniform across fq of a q-row
        mrow = mn;
        lrow *= fac;  // valid on per-lane partial sums
#pragma unroll
        for (int dt = 0; dt < 4; ++dt)
#pragma unroll
          for (int r = 0; r < 4; ++r) acc[dt][r] *= fac;
      }
      float sum = 0.f;
#pragma unroll
      for (int c = 0; c < 4; ++c) {
        bf16x4 pc;
#pragma unroll
        for (int r = 0; r < 4; ++r) {
          const float p = fexp2(s[c][r] - mn);
          sum += p;
          pc[r] = (__bf16)p;
        }
        const int bo = (c * 32 + fq * 8) ^ swz;
        *reinterpret_cast<bf16x4*>(sPb + fr * 128 + bo) = pc;
      }
      lrow += sum;  // cross-lane reduction deferred to epilogue

      bf16x8 pa[2];
#pragma unroll
      for (int ks = 0; ks < 2; ++ks) {
        const int bo = (ks * 64 + fq * 16) ^ swz;
        pa[ks] = *reinterpret_cast<const bf16x8*>(sPb + fr * 128 + bo);
      }

      __builtin_amdgcn_s_setprio(1);
#pragma unroll
      for (int dt = 0; dt < 4; ++dt) {
        const int row = dt * 16 + fr;
        bf16x8 vf0 = *reinterpret_cast<const bf16x8*>(
            vb + row * 128 + ((fq * 16) ^ swz));
        bf16x8 vf1 = *reinterpret_cast<const bf16x8*>(
            vb + row * 128 + ((fq * 16 + 64) ^ swz));
        acc[dt] = mfma16(vf0, pa[0], acc[dt]);
        acc[dt] = mfma16(vf1, pa[1], acc[dt]);
      }
      __builtin_amdgcn_s_setprio(0);
    }

    __builtin_amdgcn_s_barrier();  // all warps done reading sK[cur] + sV

    // stage V(t+1) FIRST (must land by next iter), then K(t+2) (stays in
    // flight one extra iter). sV write is safe: barrier above ended PV(t).
    if (t + 1 < nt) {
      const int kvn = (t + 1) * 64;
      gload16(vh + (size_t)(q0 * 8 + srow) * S_ + kvn + scol, &sV[q0 * 512]);
      gload16(vh + (size_t)(q1 * 8 + srow) * S_ + kvn + scol, &sV[q1 * 512]);
    }
    if (t + 2 < nt) {
      const int kvn = (t + 2) * 64;
      gload16(kh + (size_t)(kvn + q0 * 8 + srow) * HD_ + scol,
              &sK[cur][q0 * 512]);
      gload16(kh + (size_t)(kvn + q1 * 8 + srow) * HD_ + scol,
              &sK[cur][q1 * 512]);
    }
    cur ^= 1;
  }

  // epilogue: finish the deferred l reduction, then lane-local store
  float lt = lrow;
  lt += __shfl_xor(lt, 16);
  lt += __shfl_xor(lt, 32);
  const int b = bh / H_, h = bh % H_;
  const float inv_l = 1.0f / lt;
  const int qrow = qbw + fr;
#pragma unroll
  for (int dt = 0; dt < 4; ++dt) {
    bf16x4 ov;
#pragma unroll
    for (int r = 0; r < 4; ++r) ov[r] = (__bf16)(acc[dt][r] * inv_l);
    *reinterpret_cast<bf16x4*>(
        &C[((size_t)(b * S_ + qrow)) * D_ + h * HD_ + dt * 16 + fq * 4]) = ov;
  }
}

// ---------------- workspace layout (bf16 elements) ---------------------------
static constexpr size_t XB_OFF = 0;
static constexpr size_t WQ_OFF = XB_OFF + (size_t)T_ * D_;
static constexpr size_t WK_OFF = WQ_OFF + (size_t)D_ * D_;
static constexpr size_t WV_OFF = WK_OFF + (size_t)D_ * D_;
static constexpr size_t WO_OFF = WV_OFF + (size_t)D_ * D_;
static constexpr size_t Q_OFF = WO_OFF + (size_t)D_ * D_;
static constexpr size_t K_OFF = Q_OFF + (size_t)T_ * D_;
static constexpr size_t V_OFF = K_OFF + (size_t)T_ * D_;
static constexpr size_t C_OFF = V_OFF + (size_t)T_ * D_;

extern "C" void kernel_launch(void* const* d_in, const int* in_sizes, int n_in,
                              void* d_out, int out_size, void* d_ws,
                              size_t ws_size, hipStream_t stream) {
  const float* x = (const float*)d_in[0];
  const float* wq = (const float*)d_in[1];
  const float* wk = (const float*)d_in[2];
  const float* wv = (const float*)d_in[3];
  const float* wo = (const float*)d_in[4];
  const float* bo = (const float*)d_in[5];
  float* out = (float*)d_out;
  __bf16* ws = (__bf16*)d_ws;

  __bf16* xb = ws + XB_OFF;
  __bf16* wqb = ws + WQ_OFF;
  __bf16* wkb = ws + WK_OFF;
  __bf16* wvb = ws + WV_OFF;
  __bf16* wob = ws + WO_OFF;
  __bf16* qbuf = ws + Q_OFF;
  __bf16* kbuf = ws + K_OFF;
  __bf16* vbuf = ws + V_OFF;
  __bf16* cbuf = ws + C_OFF;

  {
    constexpr int n4 = T_ * D_ / 4 + 4 * (D_ * D_ / 4);
    cvt_all<<<(n4 + 255) / 256, 256, 0, stream>>>(x, wq, wk, wv, wo, ws);
  }

  gemm_bt<0><<<dim3(64, 18), 256, 0, stream>>>(
      xb, wqb, wkb, wvb, qbuf, kbuf, vbuf, nullptr, nullptr);

  attn_kernel<<<dim3(1536), 256, 0, stream>>>(qbuf, kbuf, vbuf, cbuf);

  gemm_bt<1><<<dim3(64, 6), 256, 0, stream>>>(
      cbuf, wob, nullptr, nullptr, nullptr, nullptr, nullptr, out, bo);
}

// Round 26
// 114.633 us; speedup vs baseline: 1.4050x; 1.0056x over previous
//
#include <hip/hip_runtime.h>

#define B_ 4
#define S_ 2048
#define D_ 768
#define H_ 12
#define HD_ 64
#define T_ (B_ * S_)  // 8192

typedef __bf16 bf16x8 __attribute__((ext_vector_type(8)));
typedef __bf16 bf16x4 __attribute__((ext_vector_type(4)));
typedef float  f32x4  __attribute__((ext_vector_type(4)));

__device__ __forceinline__ f32x4 mfma16(bf16x8 a, bf16x8 b, f32x4 c) {
  return __builtin_amdgcn_mfma_f32_16x16x32_bf16(a, b, c, 0, 0, 0);
}

// 2^x via v_exp_f32 (scores are pre-scaled by log2e at weight-convert time)
__device__ __forceinline__ float fexp2(float x) {
  float r;
  asm("v_exp_f32 %0, %1" : "=v"(r) : "v"(x));
  return r;
}

// async global->LDS, 16B per lane. LDS dest is wave-uniform base + lane*16.
__device__ __forceinline__ void gload16(const __bf16* g, __bf16* lds) {
  __builtin_amdgcn_global_load_lds(
      (__attribute__((address_space(1))) void*)g,
      (__attribute__((address_space(3))) void*)lds, 16, 0, 0);
}

// ---------------- fused fp32 -> bf16 convert (x + 4 weights, 1 launch) -------
__global__ void cvt_all(const float* __restrict__ x,
                        const float* __restrict__ wq,
                        const float* __restrict__ wk,
                        const float* __restrict__ wv,
                        const float* __restrict__ wo,
                        __bf16* __restrict__ out) {
  constexpr int XN4 = T_ * D_ / 4;
  constexpr int WN4 = D_ * D_ / 4;
  const int i = blockIdx.x * blockDim.x + threadIdx.x;
  if (i >= XN4 + 4 * WN4) return;
  const float* src;
  int k;
  float scale = 1.0f;
  if (i < XN4) {
    src = x;
    k = i;
  } else {
    const int j = i - XN4;
    const int wsel = j / WN4;
    k = j - wsel * WN4;
    src = (wsel == 0) ? wq : (wsel == 1) ? wk : (wsel == 2) ? wv : wo;
    if (wsel == 1) scale = 0.18033688f;  // 0.125 * log2(e)
  }
  const float4 v = reinterpret_cast<const float4*>(src)[k];
  bf16x4 o;
  o[0] = (__bf16)(v.x * scale);
  o[1] = (__bf16)(v.y * scale);
  o[2] = (__bf16)(v.z * scale);
  o[3] = (__bf16)(v.w * scale);
  reinterpret_cast<bf16x4*>(out)[i] = o;
}

// ---------------- GEMM: C[m][n] = sum_k A[m][k] * W[n][k]  (B^T layout) ------
// r26: SINGLE-BUFFER B (r25's proven attn-V pattern ported): B(t) is consumed
// only in compute(t); B(t+1) fill is issued after the post-compute barrier.
// LDS 64->48 KB -> 3 blocks/CU (was 2): +50% outstanding gload_lds per CU
// (r14/r15: fill rate scales with in-flight requests). FIFO vmcnt: prologue
// A0,B0,A1; iter top vmcnt(4) leaves only A(t+1) -> A(t)+B(t) landed; after
// compute barrier issue B(t+1) then A(t+2). Epilogue: two-pass 8 KB/wave LDS
// transpose (r23-validated) + direct vectorized V^T store.
template <int MODE>
__global__ __launch_bounds__(256)
__attribute__((amdgpu_waves_per_eu(3)))
void gemm_bt(const __bf16* __restrict__ A,
             const __bf16* __restrict__ W0, const __bf16* __restrict__ W1,
             const __bf16* __restrict__ W2,
             __bf16* __restrict__ Oq, __bf16* __restrict__ Ok,
             __bf16* __restrict__ Ov,
             float* __restrict__ fout, const float* __restrict__ bias) {
  constexpr int K = D_;       // 768
  constexpr int NT = K / 64;  // 12 K-tiles
  __shared__ __align__(16) char smem[49152];  // sA dbuf 32K | sB single 16K
  __bf16* sA0 = reinterpret_cast<__bf16*>(smem);          // [2][128*64]
  __bf16* sB0 = reinterpret_cast<__bf16*>(smem + 32768);  // [128*64]

  const int tid = threadIdx.x;
  const int l = tid & 63;
  const int w = tid >> 6;

  const int flat = blockIdx.y * 64 + blockIdx.x;
  const int xcd = flat & 7;
  const int q = flat >> 3;
  const int mtile = xcd * 8 + (q & 7);
  const int pan = q >> 3;
  const int m0 = mtile * 128;

  int mat, n0;
  const __bf16* Wm;
  if (MODE == 0) {
    mat = pan / 6;
    n0 = (pan % 6) * 128;
    Wm = (mat == 0) ? W0 : (mat == 1) ? W1 : W2;
  } else {
    mat = 0;
    n0 = pan * 128;
    Wm = W0;
  }

  const int srow = l >> 3;                // 0..7
  const int scol = ((l & 7) ^ srow) * 8;  // source col (elements)
  const __bf16* gA[4];
  const __bf16* gB[4];
#pragma unroll
  for (int i = 0; i < 4; ++i) {
    const int c = w * 4 + i;
    gA[i] = A + (size_t)(m0 + c * 8 + srow) * K + scol;
    gB[i] = Wm + (size_t)(n0 + c * 8 + srow) * K + scol;
  }

  f32x4 acc[4][4] = {};
  const int wr = w >> 1, wc = w & 1;
  const int fr = l & 15, fq = l >> 4;
  const int swz = (fr & 7) << 4;

  // prologue (FIFO): A(0) x4, B(0) x4, A(1) x4  -> 12 in flight
#pragma unroll
  for (int i = 0; i < 4; ++i) gload16(gA[i], &sA0[(w * 4 + i) * 512]);
#pragma unroll
  for (int i = 0; i < 4; ++i) gload16(gB[i], &sB0[(w * 4 + i) * 512]);
#pragma unroll
  for (int i = 0; i < 4; ++i)
    gload16(gA[i] + 64, &sA0[8192 + (w * 4 + i) * 512]);

  int cur = 0;
  for (int kt = 0; kt < NT; ++kt) {
    // complete all but the newest 4 (= A(t+1)); A(t)+B(t) landed
    if (kt + 1 < NT)
      asm volatile("s_waitcnt vmcnt(4)" ::: "memory");
    else
      asm volatile("s_waitcnt vmcnt(0)" ::: "memory");
    __builtin_amdgcn_s_barrier();

    const char* ab = reinterpret_cast<const char*>(&sA0[cur * 8192]);
    const char* bb = reinterpret_cast<const char*>(sB0);
#pragma unroll
    for (int ks = 0; ks < 2; ++ks) {
      bf16x8 af[4], bfr[4];
#pragma unroll
      for (int mi = 0; mi < 4; ++mi)
        af[mi] = *reinterpret_cast<const bf16x8*>(
            ab + (wr * 64 + mi * 16 + fr) * 128 +
            ((ks * 64 + fq * 16) ^ swz));
#pragma unroll
      for (int ni = 0; ni < 4; ++ni)
        bfr[ni] = *reinterpret_cast<const bf16x8*>(
            bb + (wc * 64 + ni * 16 + fr) * 128 +
            ((ks * 64 + fq * 16) ^ swz));
#pragma unroll
      for (int mi = 0; mi < 4; ++mi)
#pragma unroll
        for (int ni = 0; ni < 4; ++ni)
          acc[mi][ni] = mfma16(af[mi], bfr[ni], acc[mi][ni]);
    }
    __builtin_amdgcn_s_barrier();  // all warps done reading sA[cur] + sB

    // stage B(t+1) FIRST (must land by next iter; sB reads ended above),
    // then A(t+2) into the freed A buffer (stays in flight one extra iter)
    if (kt + 1 < NT) {
      const int ko = (kt + 1) * 64;
#pragma unroll
      for (int i = 0; i < 4; ++i)
        gload16(gB[i] + ko, &sB0[(w * 4 + i) * 512]);
    }
    if (kt + 2 < NT) {
      const int ko = (kt + 2) * 64;
#pragma unroll
      for (int i = 0; i < 4; ++i)
        gload16(gA[i] + ko, &sA0[cur * 8192 + (w * 4 + i) * 512]);
    }
    cur ^= 1;
  }

  // ---------------- epilogue ----------------
  if (MODE == 0 && mat == 2) {
    // V^T: direct vectorized store (4 consecutive s per lane -> one 8B store)
#pragma unroll
    for (int mi = 0; mi < 4; ++mi) {
      const int mbase = m0 + wr * 64 + mi * 16 + fq * 4;
      const int b = mbase >> 11, s = mbase & (S_ - 1);
#pragma unroll
      for (int ni = 0; ni < 4; ++ni) {
        const int o = n0 + wc * 64 + ni * 16 + fr;
        const int h = o >> 6, hd = o & 63;
        bf16x4 vv;
#pragma unroll
        for (int r = 0; r < 4; ++r) vv[r] = (__bf16)acc[mi][ni][r];
        *reinterpret_cast<bf16x4*>(
            &Ov[((size_t)((b * H_ + h) * HD_ + hd)) * S_ + s]) = vv;
      }
    }
  } else {
    // LDS transpose, two 8 KB passes (wave-private [32][64] f32 region)
    float* fW = reinterpret_cast<float*>(smem) + w * 2048;
#pragma unroll
    for (int half = 0; half < 2; ++half) {
#pragma unroll
      for (int mi2 = 0; mi2 < 2; ++mi2)
#pragma unroll
        for (int ni = 0; ni < 4; ++ni)
#pragma unroll
          for (int r = 0; r < 4; ++r)
            fW[(mi2 * 16 + fq * 4 + r) * 64 + ni * 16 + fr] =
                acc[half * 2 + mi2][ni][r];
      // per-wave region: lgkm ordering within the wave suffices
      if (MODE == 1) {
        const int ocol = n0 + wc * 64 + fr * 4;
        const float4 bs = *reinterpret_cast<const float4*>(&bias[ocol]);
#pragma unroll
        for (int it = 0; it < 8; ++it) {
          const int lrow = it * 4 + fq;
          f32x4 v = *reinterpret_cast<const f32x4*>(&fW[lrow * 64 + fr * 4]);
          v[0] += bs.x;
          v[1] += bs.y;
          v[2] += bs.z;
          v[3] += bs.w;
          *reinterpret_cast<f32x4*>(
              &fout[(size_t)(m0 + wr * 64 + half * 32 + lrow) * D_ + ocol]) =
              v;
        }
      } else {
        const int o = n0 + wc * 64;  // 64-aligned -> h const
        const int h = o >> 6;
        __bf16* dst = (mat == 0) ? Oq : Ok;
#pragma unroll
        for (int it = 0; it < 8; ++it) {
          const int lrow = it * 4 + fq;
          const int m = m0 + wr * 64 + half * 32 + lrow;
          const int b = m >> 11, s = m & (S_ - 1);
          const f32x4 v =
              *reinterpret_cast<const f32x4*>(&fW[lrow * 64 + fr * 4]);
          bf16x4 ov;
#pragma unroll
          for (int r = 0; r < 4; ++r) ov[r] = (__bf16)v[r];
          *reinterpret_cast<bf16x4*>(
              &dst[((size_t)((b * H_ + h) * S_ + s)) * HD_ + fr * 4]) = ov;
        }
      }
    }
  }
}

// ---------------- causal flash attention: 64-q blocks, single-buffer V -------
// (r25-exact, passed: LDS 32 KB, defer-max, deferred l-reduction)
__global__ __launch_bounds__(256)
__attribute__((amdgpu_waves_per_eu(5)))
void attn_kernel(const __bf16* __restrict__ Q, const __bf16* __restrict__ Kt,
                 const __bf16* __restrict__ Vt, __bf16* __restrict__ C) {
  __shared__ __align__(16) __bf16 sK[2][64 * 64];  // [kv][hd], swizzled, dbuf
  __shared__ __align__(16) __bf16 sV[64 * 64];     // V^T [hd][kv], single buf
  __shared__ __align__(16) __bf16 sP[4][16 * 64];  // per-warp P (2 KB)

  const int tid = threadIdx.x;
  const int l = tid & 63;
  const int w = tid >> 6;
  const int fr = l & 15, fq = l >> 4;
  const int bx = blockIdx.x;
  const int xcd = bx & 7;
  const int j = bx >> 3;             // [0, 192)
  const int bh = xcd + 8 * (j % 6);  // head in [0, 48), 6 per XCD
  const int qtile = 31 - j / 6;      // [0, 32), deep first
  const int qb = qtile * 64;
  const int qbw = qb + w * 16;  // this warp's 16 q-rows

  const __bf16* qh = Q + (size_t)bh * S_ * HD_;
  const __bf16* kh = Kt + (size_t)bh * S_ * HD_;
  const __bf16* vh = Vt + (size_t)bh * HD_ * S_;
  char* sPb = reinterpret_cast<char*>(&sP[w][0]);

  const int srow = l >> 3;                       // 0..7
  const int scol = ((l & 7) * 8) ^ (srow << 3);  // pre-swizzled source col
  const int swz = (fr & 7) << 4;                 // read-side XOR (bytes)

  bf16x8 qf[2];
#pragma unroll
  for (int ks = 0; ks < 2; ++ks)
    qf[ks] = *reinterpret_cast<const bf16x8*>(
        &qh[(size_t)(qbw + fr) * HD_ + ks * 32 + fq * 8]);

  f32x4 acc[4] = {};
  float mrow = -1e30f, lrow = 0.f;  // lrow: per-lane PARTIAL sum (deferred)

  const int nt = qtile + 1;  // kv tiles 0 .. qb/64
  int cur = 0;
  const int q0 = 2 * w, q1 = 2 * w + 1;

  gload16(kh + (size_t)(q0 * 8 + srow) * HD_ + scol, &sK[0][q0 * 512]);
  gload16(kh + (size_t)(q1 * 8 + srow) * HD_ + scol, &sK[0][q1 * 512]);
  gload16(vh + (size_t)(q0 * 8 + srow) * S_ + scol, &sV[q0 * 512]);
  gload16(vh + (size_t)(q1 * 8 + srow) * S_ + scol, &sV[q1 * 512]);
  if (nt > 1) {
    gload16(kh + (size_t)(64 + q0 * 8 + srow) * HD_ + scol, &sK[1][q0 * 512]);
    gload16(kh + (size_t)(64 + q1 * 8 + srow) * HD_ + scol, &sK[1][q1 * 512]);
  }

  for (int t = 0; t < nt; ++t) {
    if (t + 1 < nt)
      asm volatile("s_waitcnt vmcnt(2)" ::: "memory");
    else
      asm volatile("s_waitcnt vmcnt(0)" ::: "memory");
    __builtin_amdgcn_s_barrier();  // all warps' stage(t) landed

    const int kv0 = t * 64;
    if (kv0 <= qbw + 15) {
      const char* kb = reinterpret_cast<const char*>(&sK[cur][0]);
      const char* vb = reinterpret_cast<const char*>(&sV[0]);

      f32x4 s[4];
      __builtin_amdgcn_s_setprio(1);
#pragma unroll
      for (int c = 0; c < 4; ++c) {
        const int row = c * 16 + fr;
        bf16x8 kf0 = *reinterpret_cast<const bf16x8*>(
            kb + row * 128 + ((fq * 16) ^ swz));
        bf16x8 kf1 = *reinterpret_cast<const bf16x8*>(
            kb + row * 128 + ((fq * 16 + 64) ^ swz));
        f32x4 z = {};
        z = mfma16(kf0, qf[0], z);
        z = mfma16(kf1, qf[1], z);
        s[c] = z;
      }
      __builtin_amdgcn_s_setprio(0);

      if (kv0 + 63 > qbw) {
        const int qi = qbw + fr;
#pragma unroll
        for (int c = 0; c < 4; ++c)
#pragma unroll
          for (int r = 0; r < 4; ++r) {
            const int kvi = kv0 + c * 16 + fq * 4 + r;
            if (kvi > qi) s[c][r] = -1e30f;
          }
      }

      float tm = -1e30f;
#pragma unroll
      for (int c = 0; c < 4; ++c)
#pragma unroll
        for (int r = 0; r < 4; ++r) tm = fmaxf(tm, s[c][r]);
      tm = fmaxf(tm, __shfl_xor(tm, 16));
      tm = fmaxf(tm, __shfl_xor(tm, 32));
      // defer-max (T13): skip rescale while max grows <= 8 (log2-domain)
      const bool defer = __all(tm - mrow <= 8.0f);
      const float mn = defer ? mrow : fmaxf(mrow, tm);
      if (!defer) {
        const float fac = fexp2(mrow - mn);  // uniform across fq of a q-row
        mrow = mn;
        lrow *= fac;  // valid on per-lane partial sums
#pragma unroll
        for (int dt = 0; dt < 4; ++dt)
#pragma unroll
          for (int r = 0; r < 4; ++r) acc[dt][r] *= fac;
      }
      float sum = 0.f;
#pragma unroll
      for (int c = 0; c < 4; ++c) {
        bf16x4 pc;
#pragma unroll
        for (int r = 0; r < 4; ++r) {
          const float p = fexp2(s[c][r] - mn);
          sum += p;
          pc[r] = (__bf16)p;
        }
        const int bo = (c * 32 + fq * 8) ^ swz;
        *reinterpret_cast<bf16x4*>(sPb + fr * 128 + bo) = pc;
      }
      lrow += sum;  // cross-lane reduction deferred to epilogue

      bf16x8 pa[2];
#pragma unroll
      for (int ks = 0; ks < 2; ++ks) {
        const int bo = (ks * 64 + fq * 16) ^ swz;
        pa[ks] = *reinterpret_cast<const bf16x8*>(sPb + fr * 128 + bo);
      }

      __builtin_amdgcn_s_setprio(1);
#pragma unroll
      for (int dt = 0; dt < 4; ++dt) {
        const int row = dt * 16 + fr;
        bf16x8 vf0 = *reinterpret_cast<const bf16x8*>(
            vb + row * 128 + ((fq * 16) ^ swz));
        bf16x8 vf1 = *reinterpret_cast<const bf16x8*>(
            vb + row * 128 + ((fq * 16 + 64) ^ swz));
        acc[dt] = mfma16(vf0, pa[0], acc[dt]);
        acc[dt] = mfma16(vf1, pa[1], acc[dt]);
      }
      __builtin_amdgcn_s_setprio(0);
    }

    __builtin_amdgcn_s_barrier();  // all warps done reading sK[cur] + sV

    if (t + 1 < nt) {
      const int kvn = (t + 1) * 64;
      gload16(vh + (size_t)(q0 * 8 + srow) * S_ + kvn + scol, &sV[q0 * 512]);
      gload16(vh + (size_t)(q1 * 8 + srow) * S_ + kvn + scol, &sV[q1 * 512]);
    }
    if (t + 2 < nt) {
      const int kvn = (t + 2) * 64;
      gload16(kh + (size_t)(kvn + q0 * 8 + srow) * HD_ + scol,
              &sK[cur][q0 * 512]);
      gload16(kh + (size_t)(kvn + q1 * 8 + srow) * HD_ + scol,
              &sK[cur][q1 * 512]);
    }
    cur ^= 1;
  }

  float lt = lrow;
  lt += __shfl_xor(lt, 16);
  lt += __shfl_xor(lt, 32);
  const int b = bh / H_, h = bh % H_;
  const float inv_l = 1.0f / lt;
  const int qrow = qbw + fr;
#pragma unroll
  for (int dt = 0; dt < 4; ++dt) {
    bf16x4 ov;
#pragma unroll
    for (int r = 0; r < 4; ++r) ov[r] = (__bf16)(acc[dt][r] * inv_l);
    *reinterpret_cast<bf16x4*>(
        &C[((size_t)(b * S_ + qrow)) * D_ + h * HD_ + dt * 16 + fq * 4]) = ov;
  }
}

// ---------------- workspace layout (bf16 elements) ---------------------------
static constexpr size_t XB_OFF = 0;
static constexpr size_t WQ_OFF = XB_OFF + (size_t)T_ * D_;
static constexpr size_t WK_OFF = WQ_OFF + (size_t)D_ * D_;
static constexpr size_t WV_OFF = WK_OFF + (size_t)D_ * D_;
static constexpr size_t WO_OFF = WV_OFF + (size_t)D_ * D_;
static constexpr size_t Q_OFF = WO_OFF + (size_t)D_ * D_;
static constexpr size_t K_OFF = Q_OFF + (size_t)T_ * D_;
static constexpr size_t V_OFF = K_OFF + (size_t)T_ * D_;
static constexpr size_t C_OFF = V_OFF + (size_t)T_ * D_;

extern "C" void kernel_launch(void* const* d_in, const int* in_sizes, int n_in,
                              void* d_out, int out_size, void* d_ws,
                              size_t ws_size, hipStream_t stream) {
  const float* x = (const float*)d_in[0];
  const float* wq = (const float*)d_in[1];
  const float* wk = (const float*)d_in[2];
  const float* wv = (const float*)d_in[3];
  const float* wo = (const float*)d_in[4];
  const float* bo = (const float*)d_in[5];
  float* out = (float*)d_out;
  __bf16* ws = (__bf16*)d_ws;

  __bf16* xb = ws + XB_OFF;
  __bf16* wqb = ws + WQ_OFF;
  __bf16* wkb = ws + WK_OFF;
  __bf16* wvb = ws + WV_OFF;
  __bf16* wob = ws + WO_OFF;
  __bf16* qbuf = ws + Q_OFF;
  __bf16* kbuf = ws + K_OFF;
  __bf16* vbuf = ws + V_OFF;
  __bf16* cbuf = ws + C_OFF;

  {
    constexpr int n4 = T_ * D_ / 4 + 4 * (D_ * D_ / 4);
    cvt_all<<<(n4 + 255) / 256, 256, 0, stream>>>(x, wq, wk, wv, wo, ws);
  }

  gemm_bt<0><<<dim3(64, 18), 256, 0, stream>>>(
      xb, wqb, wkb, wvb, qbuf, kbuf, vbuf, nullptr, nullptr);

  attn_kernel<<<dim3(1536), 256, 0, stream>>>(qbuf, kbuf, vbuf, cbuf);

  gemm_bt<1><<<dim3(64, 6), 256, 0, stream>>>(
      cbuf, wob, nullptr, nullptr, nullptr, nullptr, nullptr, out, bo);
}

// Round 27
// 111.931 us; speedup vs baseline: 1.4389x; 1.0241x over previous
//
#include <hip/hip_runtime.h>

#define B_ 4
#define S_ 2048
#define D_ 768
#define H_ 12
#define HD_ 64
#define T_ (B_ * S_)  // 8192

typedef __bf16 bf16x8 __attribute__((ext_vector_type(8)));
typedef __bf16 bf16x4 __attribute__((ext_vector_type(4)));
typedef float  f32x4  __attribute__((ext_vector_type(4)));

__device__ __forceinline__ f32x4 mfma16(bf16x8 a, bf16x8 b, f32x4 c) {
  return __builtin_amdgcn_mfma_f32_16x16x32_bf16(a, b, c, 0, 0, 0);
}

// 2^x via v_exp_f32 (scores are pre-scaled by log2e at weight-convert time)
__device__ __forceinline__ float fexp2(float x) {
  float r;
  asm("v_exp_f32 %0, %1" : "=v"(r) : "v"(x));
  return r;
}

// async global->LDS, 16B per lane. LDS dest is wave-uniform base + lane*16.
__device__ __forceinline__ void gload16(const __bf16* g, __bf16* lds) {
  __builtin_amdgcn_global_load_lds(
      (__attribute__((address_space(1))) void*)g,
      (__attribute__((address_space(3))) void*)lds, 16, 0, 0);
}

// ---------------- fused fp32 -> bf16 convert (x + 4 weights, 1 launch) -------
__global__ void cvt_all(const float* __restrict__ x,
                        const float* __restrict__ wq,
                        const float* __restrict__ wk,
                        const float* __restrict__ wv,
                        const float* __restrict__ wo,
                        __bf16* __restrict__ out) {
  constexpr int XN4 = T_ * D_ / 4;
  constexpr int WN4 = D_ * D_ / 4;
  const int i = blockIdx.x * blockDim.x + threadIdx.x;
  if (i >= XN4 + 4 * WN4) return;
  const float* src;
  int k;
  float scale = 1.0f;
  if (i < XN4) {
    src = x;
    k = i;
  } else {
    const int j = i - XN4;
    const int wsel = j / WN4;
    k = j - wsel * WN4;
    src = (wsel == 0) ? wq : (wsel == 1) ? wk : (wsel == 2) ? wv : wo;
    if (wsel == 1) scale = 0.18033688f;  // 0.125 * log2(e)
  }
  const float4 v = reinterpret_cast<const float4*>(src)[k];
  bf16x4 o;
  o[0] = (__bf16)(v.x * scale);
  o[1] = (__bf16)(v.y * scale);
  o[2] = (__bf16)(v.z * scale);
  o[3] = (__bf16)(v.w * scale);
  reinterpret_cast<bf16x4*>(out)[i] = o;
}

// ---------------- GEMM: C[m][n] = sum_k A[m][k] * W[n][k]  (B^T layout) ------
// r26-exact: 128x128, BK=64, A dbuf + B single-buffer (48 KB LDS, 3 blk/CU),
// counted vmcnt (top vmcnt(4): A(t)+B(t) landed, A(t+1) in flight; post-
// barrier issue B(t+1) then A(t+2)), swizzled LDS, XCD-slab remap, two-pass
// LDS-transpose epilogue + direct vectorized V^T store.
template <int MODE>
__global__ __launch_bounds__(256)
__attribute__((amdgpu_waves_per_eu(3)))
void gemm_bt(const __bf16* __restrict__ A,
             const __bf16* __restrict__ W0, const __bf16* __restrict__ W1,
             const __bf16* __restrict__ W2,
             __bf16* __restrict__ Oq, __bf16* __restrict__ Ok,
             __bf16* __restrict__ Ov,
             float* __restrict__ fout, const float* __restrict__ bias) {
  constexpr int K = D_;       // 768
  constexpr int NT = K / 64;  // 12 K-tiles
  __shared__ __align__(16) char smem[49152];  // sA dbuf 32K | sB single 16K
  __bf16* sA0 = reinterpret_cast<__bf16*>(smem);          // [2][128*64]
  __bf16* sB0 = reinterpret_cast<__bf16*>(smem + 32768);  // [128*64]

  const int tid = threadIdx.x;
  const int l = tid & 63;
  const int w = tid >> 6;

  const int flat = blockIdx.y * 64 + blockIdx.x;
  const int xcd = flat & 7;
  const int q = flat >> 3;
  const int mtile = xcd * 8 + (q & 7);
  const int pan = q >> 3;
  const int m0 = mtile * 128;

  int mat, n0;
  const __bf16* Wm;
  if (MODE == 0) {
    mat = pan / 6;
    n0 = (pan % 6) * 128;
    Wm = (mat == 0) ? W0 : (mat == 1) ? W1 : W2;
  } else {
    mat = 0;
    n0 = pan * 128;
    Wm = W0;
  }

  const int srow = l >> 3;                // 0..7
  const int scol = ((l & 7) ^ srow) * 8;  // source col (elements)
  const __bf16* gA[4];
  const __bf16* gB[4];
#pragma unroll
  for (int i = 0; i < 4; ++i) {
    const int c = w * 4 + i;
    gA[i] = A + (size_t)(m0 + c * 8 + srow) * K + scol;
    gB[i] = Wm + (size_t)(n0 + c * 8 + srow) * K + scol;
  }

  f32x4 acc[4][4] = {};
  const int wr = w >> 1, wc = w & 1;
  const int fr = l & 15, fq = l >> 4;
  const int swz = (fr & 7) << 4;

  // prologue (FIFO): A(0) x4, B(0) x4, A(1) x4  -> 12 in flight
#pragma unroll
  for (int i = 0; i < 4; ++i) gload16(gA[i], &sA0[(w * 4 + i) * 512]);
#pragma unroll
  for (int i = 0; i < 4; ++i) gload16(gB[i], &sB0[(w * 4 + i) * 512]);
#pragma unroll
  for (int i = 0; i < 4; ++i)
    gload16(gA[i] + 64, &sA0[8192 + (w * 4 + i) * 512]);

  int cur = 0;
  for (int kt = 0; kt < NT; ++kt) {
    if (kt + 1 < NT)
      asm volatile("s_waitcnt vmcnt(4)" ::: "memory");
    else
      asm volatile("s_waitcnt vmcnt(0)" ::: "memory");
    __builtin_amdgcn_s_barrier();

    const char* ab = reinterpret_cast<const char*>(&sA0[cur * 8192]);
    const char* bb = reinterpret_cast<const char*>(sB0);
#pragma unroll
    for (int ks = 0; ks < 2; ++ks) {
      bf16x8 af[4], bfr[4];
#pragma unroll
      for (int mi = 0; mi < 4; ++mi)
        af[mi] = *reinterpret_cast<const bf16x8*>(
            ab + (wr * 64 + mi * 16 + fr) * 128 +
            ((ks * 64 + fq * 16) ^ swz));
#pragma unroll
      for (int ni = 0; ni < 4; ++ni)
        bfr[ni] = *reinterpret_cast<const bf16x8*>(
            bb + (wc * 64 + ni * 16 + fr) * 128 +
            ((ks * 64 + fq * 16) ^ swz));
#pragma unroll
      for (int mi = 0; mi < 4; ++mi)
#pragma unroll
        for (int ni = 0; ni < 4; ++ni)
          acc[mi][ni] = mfma16(af[mi], bfr[ni], acc[mi][ni]);
    }
    __builtin_amdgcn_s_barrier();  // all warps done reading sA[cur] + sB

    if (kt + 1 < NT) {
      const int ko = (kt + 1) * 64;
#pragma unroll
      for (int i = 0; i < 4; ++i)
        gload16(gB[i] + ko, &sB0[(w * 4 + i) * 512]);
    }
    if (kt + 2 < NT) {
      const int ko = (kt + 2) * 64;
#pragma unroll
      for (int i = 0; i < 4; ++i)
        gload16(gA[i] + ko, &sA0[cur * 8192 + (w * 4 + i) * 512]);
    }
    cur ^= 1;
  }

  // ---------------- epilogue ----------------
  if (MODE == 0 && mat == 2) {
#pragma unroll
    for (int mi = 0; mi < 4; ++mi) {
      const int mbase = m0 + wr * 64 + mi * 16 + fq * 4;
      const int b = mbase >> 11, s = mbase & (S_ - 1);
#pragma unroll
      for (int ni = 0; ni < 4; ++ni) {
        const int o = n0 + wc * 64 + ni * 16 + fr;
        const int h = o >> 6, hd = o & 63;
        bf16x4 vv;
#pragma unroll
        for (int r = 0; r < 4; ++r) vv[r] = (__bf16)acc[mi][ni][r];
        *reinterpret_cast<bf16x4*>(
            &Ov[((size_t)((b * H_ + h) * HD_ + hd)) * S_ + s]) = vv;
      }
    }
  } else {
    float* fW = reinterpret_cast<float*>(smem) + w * 2048;
#pragma unroll
    for (int half = 0; half < 2; ++half) {
#pragma unroll
      for (int mi2 = 0; mi2 < 2; ++mi2)
#pragma unroll
        for (int ni = 0; ni < 4; ++ni)
#pragma unroll
          for (int r = 0; r < 4; ++r)
            fW[(mi2 * 16 + fq * 4 + r) * 64 + ni * 16 + fr] =
                acc[half * 2 + mi2][ni][r];
      if (MODE == 1) {
        const int ocol = n0 + wc * 64 + fr * 4;
        const float4 bs = *reinterpret_cast<const float4*>(&bias[ocol]);
#pragma unroll
        for (int it = 0; it < 8; ++it) {
          const int lrow = it * 4 + fq;
          f32x4 v = *reinterpret_cast<const f32x4*>(&fW[lrow * 64 + fr * 4]);
          v[0] += bs.x;
          v[1] += bs.y;
          v[2] += bs.z;
          v[3] += bs.w;
          *reinterpret_cast<f32x4*>(
              &fout[(size_t)(m0 + wr * 64 + half * 32 + lrow) * D_ + ocol]) =
              v;
        }
      } else {
        const int o = n0 + wc * 64;  // 64-aligned -> h const
        const int h = o >> 6;
        __bf16* dst = (mat == 0) ? Oq : Ok;
#pragma unroll
        for (int it = 0; it < 8; ++it) {
          const int lrow = it * 4 + fq;
          const int m = m0 + wr * 64 + half * 32 + lrow;
          const int b = m >> 11, s = m & (S_ - 1);
          const f32x4 v =
              *reinterpret_cast<const f32x4*>(&fW[lrow * 64 + fr * 4]);
          bf16x4 ov;
#pragma unroll
          for (int r = 0; r < 4; ++r) ov[r] = (__bf16)v[r];
          *reinterpret_cast<bf16x4*>(
              &dst[((size_t)((b * H_ + h) * S_ + s)) * HD_ + fr * 4]) = ov;
        }
      }
    }
  }
}

// ---------------- causal flash attention: 64-q blocks, single-buffer V -------
// r27 change (only): VOTE-FIRST defer check. The defer decision does not need
// the per-row reduced max: __all(tm_lane_local - mrow <= 8) over the wave is
// logically identical to comparing the shfl-reduced per-row max (conjunction
// of per-lane comparisons). So the 2 __shfl_xor ops (~200 cy LDS-pipe) move
// INSIDE the rare non-defer branch; the common-path tile has zero cross-lane
// data movement (l-reduction already deferred to epilogue). Tile 0 takes the
// non-defer path naturally (mrow = -1e30). Numerics exact.
__global__ __launch_bounds__(256)
__attribute__((amdgpu_waves_per_eu(5)))
void attn_kernel(const __bf16* __restrict__ Q, const __bf16* __restrict__ Kt,
                 const __bf16* __restrict__ Vt, __bf16* __restrict__ C) {
  __shared__ __align__(16) __bf16 sK[2][64 * 64];  // [kv][hd], swizzled, dbuf
  __shared__ __align__(16) __bf16 sV[64 * 64];     // V^T [hd][kv], single buf
  __shared__ __align__(16) __bf16 sP[4][16 * 64];  // per-warp P (2 KB)

  const int tid = threadIdx.x;
  const int l = tid & 63;
  const int w = tid >> 6;
  const int fr = l & 15, fq = l >> 4;
  const int bx = blockIdx.x;
  const int xcd = bx & 7;
  const int j = bx >> 3;             // [0, 192)
  const int bh = xcd + 8 * (j % 6);  // head in [0, 48), 6 per XCD
  const int qtile = 31 - j / 6;      // [0, 32), deep first
  const int qb = qtile * 64;
  const int qbw = qb + w * 16;  // this warp's 16 q-rows

  const __bf16* qh = Q + (size_t)bh * S_ * HD_;
  const __bf16* kh = Kt + (size_t)bh * S_ * HD_;
  const __bf16* vh = Vt + (size_t)bh * HD_ * S_;
  char* sPb = reinterpret_cast<char*>(&sP[w][0]);

  const int srow = l >> 3;                       // 0..7
  const int scol = ((l & 7) * 8) ^ (srow << 3);  // pre-swizzled source col
  const int swz = (fr & 7) << 4;                 // read-side XOR (bytes)

  bf16x8 qf[2];
#pragma unroll
  for (int ks = 0; ks < 2; ++ks)
    qf[ks] = *reinterpret_cast<const bf16x8*>(
        &qh[(size_t)(qbw + fr) * HD_ + ks * 32 + fq * 8]);

  f32x4 acc[4] = {};
  float mrow = -1e30f, lrow = 0.f;  // lrow: per-lane PARTIAL sum (deferred)

  const int nt = qtile + 1;  // kv tiles 0 .. qb/64
  int cur = 0;
  const int q0 = 2 * w, q1 = 2 * w + 1;

  gload16(kh + (size_t)(q0 * 8 + srow) * HD_ + scol, &sK[0][q0 * 512]);
  gload16(kh + (size_t)(q1 * 8 + srow) * HD_ + scol, &sK[0][q1 * 512]);
  gload16(vh + (size_t)(q0 * 8 + srow) * S_ + scol, &sV[q0 * 512]);
  gload16(vh + (size_t)(q1 * 8 + srow) * S_ + scol, &sV[q1 * 512]);
  if (nt > 1) {
    gload16(kh + (size_t)(64 + q0 * 8 + srow) * HD_ + scol, &sK[1][q0 * 512]);
    gload16(kh + (size_t)(64 + q1 * 8 + srow) * HD_ + scol, &sK[1][q1 * 512]);
  }

  for (int t = 0; t < nt; ++t) {
    if (t + 1 < nt)
      asm volatile("s_waitcnt vmcnt(2)" ::: "memory");
    else
      asm volatile("s_waitcnt vmcnt(0)" ::: "memory");
    __builtin_amdgcn_s_barrier();  // all warps' stage(t) landed

    const int kv0 = t * 64;
    if (kv0 <= qbw + 15) {
      const char* kb = reinterpret_cast<const char*>(&sK[cur][0]);
      const char* vb = reinterpret_cast<const char*>(&sV[0]);

      f32x4 s[4];
      __builtin_amdgcn_s_setprio(1);
#pragma unroll
      for (int c = 0; c < 4; ++c) {
        const int row = c * 16 + fr;
        bf16x8 kf0 = *reinterpret_cast<const bf16x8*>(
            kb + row * 128 + ((fq * 16) ^ swz));
        bf16x8 kf1 = *reinterpret_cast<const bf16x8*>(
            kb + row * 128 + ((fq * 16 + 64) ^ swz));
        f32x4 z = {};
        z = mfma16(kf0, qf[0], z);
        z = mfma16(kf1, qf[1], z);
        s[c] = z;
      }
      __builtin_amdgcn_s_setprio(0);

      if (kv0 + 63 > qbw) {
        const int qi = qbw + fr;
#pragma unroll
        for (int c = 0; c < 4; ++c)
#pragma unroll
          for (int r = 0; r < 4; ++r) {
            const int kvi = kv0 + c * 16 + fq * 4 + r;
            if (kvi > qi) s[c][r] = -1e30f;
          }
      }

      // lane-local max tree; vote-first defer (no shfl on common path)
      float tml = -1e30f;
#pragma unroll
      for (int c = 0; c < 4; ++c)
#pragma unroll
        for (int r = 0; r < 4; ++r) tml = fmaxf(tml, s[c][r]);
      const bool defer = __all(tml - mrow <= 8.0f);
      float mn;
      if (defer) {
        mn = mrow;
      } else {
        float tm = fmaxf(tml, __shfl_xor(tml, 16));
        tm = fmaxf(tm, __shfl_xor(tm, 32));
        mn = fmaxf(mrow, tm);
        const float fac = fexp2(mrow - mn);  // uniform across fq of a q-row
        mrow = mn;
        lrow *= fac;  // valid on per-lane partial sums
#pragma unroll
        for (int dt = 0; dt < 4; ++dt)
#pragma unroll
          for (int r = 0; r < 4; ++r) acc[dt][r] *= fac;
      }
      float sum = 0.f;
#pragma unroll
      for (int c = 0; c < 4; ++c) {
        bf16x4 pc;
#pragma unroll
        for (int r = 0; r < 4; ++r) {
          const float p = fexp2(s[c][r] - mn);
          sum += p;
          pc[r] = (__bf16)p;
        }
        const int bo = (c * 32 + fq * 8) ^ swz;
        *reinterpret_cast<bf16x4*>(sPb + fr * 128 + bo) = pc;
      }
      lrow += sum;  // cross-lane reduction deferred to epilogue

      bf16x8 pa[2];
#pragma unroll
      for (int ks = 0; ks < 2; ++ks) {
        const int bo = (ks * 64 + fq * 16) ^ swz;
        pa[ks] = *reinterpret_cast<const bf16x8*>(sPb + fr * 128 + bo);
      }

      __builtin_amdgcn_s_setprio(1);
#pragma unroll
      for (int dt = 0; dt < 4; ++dt) {
        const int row = dt * 16 + fr;
        bf16x8 vf0 = *reinterpret_cast<const bf16x8*>(
            vb + row * 128 + ((fq * 16) ^ swz));
        bf16x8 vf1 = *reinterpret_cast<const bf16x8*>(
            vb + row * 128 + ((fq * 16 + 64) ^ swz));
        acc[dt] = mfma16(vf0, pa[0], acc[dt]);
        acc[dt] = mfma16(vf1, pa[1], acc[dt]);
      }
      __builtin_amdgcn_s_setprio(0);
    }

    __builtin_amdgcn_s_barrier();  // all warps done reading sK[cur] + sV

    if (t + 1 < nt) {
      const int kvn = (t + 1) * 64;
      gload16(vh + (size_t)(q0 * 8 + srow) * S_ + kvn + scol, &sV[q0 * 512]);
      gload16(vh + (size_t)(q1 * 8 + srow) * S_ + kvn + scol, &sV[q1 * 512]);
    }
    if (t + 2 < nt) {
      const int kvn = (t + 2) * 64;
      gload16(kh + (size_t)(kvn + q0 * 8 + srow) * HD_ + scol,
              &sK[cur][q0 * 512]);
      gload16(kh + (size_t)(kvn + q1 * 8 + srow) * HD_ + scol,
              &sK[cur][q1 * 512]);
    }
    cur ^= 1;
  }

  float lt = lrow;
  lt += __shfl_xor(lt, 16);
  lt += __shfl_xor(lt, 32);
  const int b = bh / H_, h = bh % H_;
  const float inv_l = 1.0f / lt;
  const int qrow = qbw + fr;
#pragma unroll
  for (int dt = 0; dt < 4; ++dt) {
    bf16x4 ov;
#pragma unroll
    for (int r = 0; r < 4; ++r) ov[r] = (__bf16)(acc[dt][r] * inv_l);
    *reinterpret_cast<bf16x4*>(
        &C[((size_t)(b * S_ + qrow)) * D_ + h * HD_ + dt * 16 + fq * 4]) = ov;
  }
}

// ---------------- workspace layout (bf16 elements) ---------------------------
static constexpr size_t XB_OFF = 0;
static constexpr size_t WQ_OFF = XB_OFF + (size_t)T_ * D_;
static constexpr size_t WK_OFF = WQ_OFF + (size_t)D_ * D_;
static constexpr size_t WV_OFF = WK_OFF + (size_t)D_ * D_;
static constexpr size_t WO_OFF = WV_OFF + (size_t)D_ * D_;
static constexpr size_t Q_OFF = WO_OFF + (size_t)D_ * D_;
static constexpr size_t K_OFF = Q_OFF + (size_t)T_ * D_;
static constexpr size_t V_OFF = K_OFF + (size_t)T_ * D_;
static constexpr size_t C_OFF = V_OFF + (size_t)T_ * D_;

extern "C" void kernel_launch(void* const* d_in, const int* in_sizes, int n_in,
                              void* d_out, int out_size, void* d_ws,
                              size_t ws_size, hipStream_t stream) {
  const float* x = (const float*)d_in[0];
  const float* wq = (const float*)d_in[1];
  const float* wk = (const float*)d_in[2];
  const float* wv = (const float*)d_in[3];
  const float* wo = (const float*)d_in[4];
  const float* bo = (const float*)d_in[5];
  float* out = (float*)d_out;
  __bf16* ws = (__bf16*)d_ws;

  __bf16* xb = ws + XB_OFF;
  __bf16* wqb = ws + WQ_OFF;
  __bf16* wkb = ws + WK_OFF;
  __bf16* wvb = ws + WV_OFF;
  __bf16* wob = ws + WO_OFF;
  __bf16* qbuf = ws + Q_OFF;
  __bf16* kbuf = ws + K_OFF;
  __bf16* vbuf = ws + V_OFF;
  __bf16* cbuf = ws + C_OFF;

  {
    constexpr int n4 = T_ * D_ / 4 + 4 * (D_ * D_ / 4);
    cvt_all<<<(n4 + 255) / 256, 256, 0, stream>>>(x, wq, wk, wv, wo, ws);
  }

  gemm_bt<0><<<dim3(64, 18), 256, 0, stream>>>(
      xb, wqb, wkb, wvb, qbuf, kbuf, vbuf, nullptr, nullptr);

  attn_kernel<<<dim3(1536), 256, 0, stream>>>(qbuf, kbuf, vbuf, cbuf);

  gemm_bt<1><<<dim3(64, 6), 256, 0, stream>>>(
      cbuf, wob, nullptr, nullptr, nullptr, nullptr, nullptr, out, bo);
}